// Round 1
// baseline (1056.145 us; speedup 1.0000x reference)
//
#include <hip/hip_runtime.h>
#include <math.h>

#define N_USER 100000
#define N_ITEM 150000
#define NTOT   250000
#define D64    64
#define NNZ    1250000
#define BATCH  16384
#define GD     16
#define DSTATE 8
#define DCONV  4
#define DINNER 32
#define LSEQ   3

// ---------------- zero fill (graph-capture-safe, replaces memset) ----------
__global__ void zero_kernel(float4* __restrict__ p, int n4) {
    int i = blockIdx.x * blockDim.x + threadIdx.x;
    if (i < n4) p[i] = make_float4(0.f, 0.f, 0.f, 0.f);
}

// ---------------- GNN scatter: wave per edge, lane = feature dim -----------
// srcEmb == nullptr -> read from concat(user,item); else from srcEmb.
__global__ void scatter_kernel(const float* __restrict__ user,
                               const float* __restrict__ item,
                               const float* __restrict__ srcEmb,
                               const int*   __restrict__ erow,
                               const int*   __restrict__ ecol,
                               const float* __restrict__ eval_,
                               float*       __restrict__ acc) {
    int e    = blockIdx.x * 4 + (threadIdx.x >> 6);
    int lane = threadIdx.x & 63;
    if (e >= NNZ) return;
    int   c = ecol[e];
    int   r = erow[e];
    float v = eval_[e];
    const float* src;
    if (srcEmb) src = srcEmb + (size_t)c * D64;
    else        src = (c < N_USER) ? (user + (size_t)c * D64)
                                   : (item + (size_t)(c - N_USER) * D64);
    unsafeAtomicAdd(&acc[(size_t)r * D64 + lane], v * src[lane]);
}

// ---------------- row L2 normalize, in place: wave per row -----------------
__global__ void normalize_kernel(float* __restrict__ emb) {
    int r    = blockIdx.x * 4 + (threadIdx.x >> 6);
    int lane = threadIdx.x & 63;
    if (r >= NTOT) return;
    size_t idx = (size_t)r * D64 + lane;
    float v = emb[idx];
    float s = v * v;
    #pragma unroll
    for (int m = 32; m >= 1; m >>= 1) s += __shfl_xor(s, m, 64);
    float scale = 1.0f / fmaxf(sqrtf(s), 1e-12f);
    emb[idx] = v * scale;
}

// ---------------- gather the 3-step sequence per batch node ----------------
__global__ void gather_seq_kernel(const float* __restrict__ user,
                                  const float* __restrict__ item,
                                  const float* __restrict__ embA,
                                  const float* __restrict__ embB,
                                  const int*   __restrict__ nids,
                                  float*       __restrict__ seq) {
    int t = blockIdx.x * blockDim.x + threadIdx.x;
    if (t >= BATCH * D64) return;
    int b = t >> 6, d = t & 63;
    int nid = nids[b];
    float v0 = (nid < N_USER) ? user[(size_t)nid * D64 + d]
                              : item[(size_t)(nid - N_USER) * D64 + d];
    size_t base = ((size_t)b * LSEQ) * D64 + d;
    seq[base]            = v0;
    seq[base + D64]      = embA[(size_t)nid * D64 + d];
    seq[base + 2 * D64]  = embB[(size_t)nid * D64 + d];
}

// ---------------- fused head: down-proj + mamba + LN + softmax fuse --------
// One thread per batch element. block=64 (one wave), __launch_bounds__(64,1)
// gives the register allocator a 512-VGPR budget -> no scratch spills for
// the fully unrolled ~280-reg body.
__global__ __launch_bounds__(64, 1) void final_kernel(
    const float* __restrict__ seq,
    const float* __restrict__ down_w,    const float* __restrict__ in_proj_w,
    const float* __restrict__ conv_w,    const float* __restrict__ conv_b,
    const float* __restrict__ x_proj_w,  const float* __restrict__ dt_proj_w,
    const float* __restrict__ dt_proj_b, const float* __restrict__ A_log,
    const float* __restrict__ D_param,   const float* __restrict__ out_proj_w,
    const float* __restrict__ ln_g,      const float* __restrict__ ln_b,
    const float* __restrict__ to_logit_w,const float* __restrict__ to_logit_b,
    float* __restrict__ out) {

    __shared__ float s_down[GD * D64];          // [j][d64]
    __shared__ float s_ip[2 * DINNER * GD];     // [row][j]  rows 0..31 = x, 32..63 = z
    __shared__ float s_xp[(1 + 2 * DSTATE) * DINNER];
    __shared__ float s_cw[DINNER * DCONV];
    __shared__ float s_cb[DINNER];
    __shared__ float s_dtw[DINNER];
    __shared__ float s_dtb[DINNER];
    __shared__ float s_A[DINNER * DSTATE];      // A = -exp(A_log)
    __shared__ float s_Dp[DINNER];
    __shared__ float s_op[GD * DINNER];         // [j][d]
    __shared__ float s_lng[GD], s_lnb[GD], s_lw[GD];
    __shared__ float s_lb;

    int t = threadIdx.x;
    for (int i = t; i < GD * D64; i += 64)        s_down[i] = down_w[i];
    for (int i = t; i < 2 * DINNER * GD; i += 64) s_ip[i]   = in_proj_w[i];
    for (int i = t; i < 17 * DINNER; i += 64)     s_xp[i]   = x_proj_w[i];
    for (int i = t; i < DINNER * DCONV; i += 64)  s_cw[i]   = conv_w[i];
    for (int i = t; i < DINNER * DSTATE; i += 64) s_A[i]    = -expf(A_log[i]);
    for (int i = t; i < GD * DINNER; i += 64)     s_op[i]   = out_proj_w[i];
    if (t < DINNER) {
        s_cb[t] = conv_b[t]; s_dtw[t] = dt_proj_w[t];
        s_dtb[t] = dt_proj_b[t]; s_Dp[t] = D_param[t];
    }
    if (t < GD) { s_lng[t] = ln_g[t]; s_lnb[t] = ln_b[t]; s_lw[t] = to_logit_w[t]; }
    if (t == 0) s_lb = to_logit_b[0];
    __syncthreads();

    int b = blockIdx.x * 64 + t;
    if (b >= BATCH) return;
    const float* sq = seq + (size_t)b * (LSEQ * D64);

    // ---- g = seq @ down_w.T : (3,16) ----
    float g[LSEQ][GD];
    #pragma unroll
    for (int l = 0; l < LSEQ; ++l) {
        float sl[D64];
        const float4* s4 = (const float4*)(sq + l * D64);
        #pragma unroll
        for (int q = 0; q < D64 / 4; ++q) {
            float4 v = s4[q];
            sl[4*q+0] = v.x; sl[4*q+1] = v.y; sl[4*q+2] = v.z; sl[4*q+3] = v.w;
        }
        #pragma unroll
        for (int j = 0; j < GD; ++j) {
            float a = 0.f;
            #pragma unroll
            for (int d = 0; d < D64; ++d) a = fmaf(sl[d], s_down[j * D64 + d], a);
            g[l][j] = a;
        }
    }

    // ---- x-branch of in_proj : (3,32) ----
    float xl[LSEQ][DINNER];
    #pragma unroll
    for (int l = 0; l < LSEQ; ++l)
        #pragma unroll
        for (int d = 0; d < DINNER; ++d) {
            float a = 0.f;
            #pragma unroll
            for (int j = 0; j < GD; ++j) a = fmaf(g[l][j], s_ip[d * GD + j], a);
            xl[l][d] = a;
        }

    // ---- causal depthwise conv (DCONV=4, left pad 3) + SiLU ----
    float xs[LSEQ][DINNER];
    #pragma unroll
    for (int l = 0; l < LSEQ; ++l)
        #pragma unroll
        for (int d = 0; d < DINNER; ++d) {
            float a = s_cb[d];
            #pragma unroll
            for (int k = 0; k < DCONV; ++k) {
                if (l + k - 3 >= 0) a = fmaf(xl[l + k - 3][d], s_cw[d * DCONV + k], a);
            }
            xs[l][d] = a / (1.f + __expf(-a));   // silu
        }

    // ---- dbc = x @ x_proj.T : dt_raw (3), B (3,8), C (3,8) ----
    float dtr[LSEQ], Bm[LSEQ][DSTATE], Cm[LSEQ][DSTATE];
    #pragma unroll
    for (int l = 0; l < LSEQ; ++l) {
        float a = 0.f;
        #pragma unroll
        for (int d = 0; d < DINNER; ++d) a = fmaf(xs[l][d], s_xp[d], a);
        dtr[l] = a;
        #pragma unroll
        for (int s = 0; s < DSTATE; ++s) {
            float ab = 0.f, ac = 0.f;
            #pragma unroll
            for (int d = 0; d < DINNER; ++d) {
                ab = fmaf(xs[l][d], s_xp[(1 + s) * DINNER + d], ab);
                ac = fmaf(xs[l][d], s_xp[(1 + DSTATE + s) * DINNER + d], ac);
            }
            Bm[l][s] = ab; Cm[l][s] = ac;
        }
    }

    // ---- selective scan, d-outer so h[] stays 8 regs; fuse z, out_proj ----
    float o[LSEQ][GD];
    #pragma unroll
    for (int l = 0; l < LSEQ; ++l)
        #pragma unroll
        for (int j = 0; j < GD; ++j) o[l][j] = 0.f;

    #pragma unroll
    for (int d = 0; d < DINNER; ++d) {
        float h[DSTATE];
        #pragma unroll
        for (int s = 0; s < DSTATE; ++s) h[s] = 0.f;
        #pragma unroll
        for (int l = 0; l < LSEQ; ++l) {
            float pre = fmaf(dtr[l], s_dtw[d], s_dtb[d]);
            float dt  = (pre > 20.f) ? pre : __logf(1.f + __expf(pre));  // softplus
            float xv  = xs[l][d];
            float acc = 0.f;
            #pragma unroll
            for (int s = 0; s < DSTATE; ++s) {
                float dA = __expf(dt * s_A[d * DSTATE + s]);
                h[s] = fmaf(dA, h[s], dt * Bm[l][s] * xv);
                acc  = fmaf(h[s], Cm[l][s], acc);
            }
            float y = fmaf(s_Dp[d], xv, acc);
            float zv = 0.f;
            #pragma unroll
            for (int j = 0; j < GD; ++j) zv = fmaf(g[l][j], s_ip[(DINNER + d) * GD + j], zv);
            float ys = y * (zv / (1.f + __expf(-zv)));   // y * silu(z)
            #pragma unroll
            for (int j = 0; j < GD; ++j) o[l][j] = fmaf(ys, s_op[j * DINNER + d], o[l][j]);
        }
    }

    // ---- residual + LayerNorm(16) + logit + softmax(T=0.8) ----
    float lg[LSEQ];
    #pragma unroll
    for (int l = 0; l < LSEQ; ++l) {
        float v[GD];
        float mu = 0.f;
        #pragma unroll
        for (int j = 0; j < GD; ++j) { v[j] = o[l][j] + g[l][j]; mu += v[j]; }
        mu *= (1.f / GD);
        float var = 0.f;
        #pragma unroll
        for (int j = 0; j < GD; ++j) { float dd = v[j] - mu; var = fmaf(dd, dd, var); }
        var *= (1.f / GD);
        float inv = rsqrtf(var + 1e-12f);
        float lo = 0.f;
        #pragma unroll
        for (int j = 0; j < GD; ++j)
            lo = fmaf(fmaf((v[j] - mu) * inv, s_lng[j], s_lnb[j]), s_lw[j], lo);
        lg[l] = (lo + s_lb) * (1.0f / 0.8f);   // /TEMP
    }
    float mx = fmaxf(lg[0], fmaxf(lg[1], lg[2]));
    float e0 = __expf(lg[0] - mx), e1 = __expf(lg[1] - mx), e2 = __expf(lg[2] - mx);
    float inv = 1.f / (e0 + e1 + e2);
    float w0 = e0 * inv, w1 = e1 * inv, w2 = e2 * inv;

    // ---- fused = sum_l w_l * seq[l] ----
    const float4* q0 = (const float4*)(sq);
    const float4* q1 = (const float4*)(sq + D64);
    const float4* q2 = (const float4*)(sq + 2 * D64);
    float4* o4 = (float4*)(out + (size_t)b * D64);
    #pragma unroll
    for (int q = 0; q < D64 / 4; ++q) {
        float4 a = q0[q], bb = q1[q], c = q2[q], r;
        r.x = w0 * a.x + w1 * bb.x + w2 * c.x;
        r.y = w0 * a.y + w1 * bb.y + w2 * c.y;
        r.z = w0 * a.z + w1 * bb.z + w2 * c.z;
        r.w = w0 * a.w + w1 * bb.w + w2 * c.w;
        o4[q] = r;
    }
}

extern "C" void kernel_launch(void* const* d_in, const int* in_sizes, int n_in,
                              void* d_out, int out_size, void* d_ws, size_t ws_size,
                              hipStream_t stream) {
    const float* user      = (const float*)d_in[0];
    const float* item      = (const float*)d_in[1];
    const int*   erow      = (const int*)  d_in[2];
    const int*   ecol      = (const int*)  d_in[3];
    const float* eval_     = (const float*)d_in[4];
    const int*   nids      = (const int*)  d_in[5];
    const float* down_w    = (const float*)d_in[6];
    const float* in_proj_w = (const float*)d_in[7];
    const float* conv_w    = (const float*)d_in[8];
    const float* conv_b    = (const float*)d_in[9];
    const float* x_proj_w  = (const float*)d_in[10];
    const float* dt_proj_w = (const float*)d_in[11];
    const float* dt_proj_b = (const float*)d_in[12];
    const float* A_log     = (const float*)d_in[13];
    const float* D_param   = (const float*)d_in[14];
    const float* out_projw = (const float*)d_in[15];
    const float* ln_g      = (const float*)d_in[16];
    const float* ln_b      = (const float*)d_in[17];
    const float* to_lw     = (const float*)d_in[18];
    const float* to_lb     = (const float*)d_in[19];
    float* out = (float*)d_out;

    float* embA = (float*)d_ws;                    // N*64 f32 = 64 MB
    float* embB = embA + (size_t)NTOT * D64;       // 64 MB
    float* seq  = embB + (size_t)NTOT * D64;       // 12.6 MB

    // zero both accumulators up front (ws is poisoned 0xAA every call)
    {
        int n4 = 2 * NTOT * D64 / 4;
        zero_kernel<<<(n4 + 255) / 256, 256, 0, stream>>>((float4*)embA, n4);
    }
    // layer 1: scatter from original embeddings into embA, then normalize
    scatter_kernel<<<NNZ / 4, 256, 0, stream>>>(user, item, nullptr, erow, ecol, eval_, embA);
    normalize_kernel<<<NTOT / 4, 256, 0, stream>>>(embA);
    // layer 2: scatter from embA into embB, then normalize
    scatter_kernel<<<NNZ / 4, 256, 0, stream>>>(user, item, embA, erow, ecol, eval_, embB);
    normalize_kernel<<<NTOT / 4, 256, 0, stream>>>(embB);
    // sequence gather + fused head
    gather_seq_kernel<<<(BATCH * D64) / 256, 256, 0, stream>>>(user, item, embA, embB, nids, seq);
    final_kernel<<<BATCH / 64, 64, 0, stream>>>(seq, down_w, in_proj_w, conv_w, conv_b,
                                                x_proj_w, dt_proj_w, dt_proj_b, A_log,
                                                D_param, out_projw, ln_g, ln_b, to_lw, to_lb, out);
}

// Round 2
// 631.039 us; speedup vs baseline: 1.6737x; 1.6737x over previous
//
#include <hip/hip_runtime.h>
#include <math.h>

#define N_USER 100000
#define N_ITEM 150000
#define NTOT   250000
#define D64    64
#define NNZ    1250000
#define BATCH  16384
#define GD     16
#define DSTATE 8
#define DCONV  4
#define DINNER 32
#define LSEQ   3
#define NBLK1  ((NTOT + 1023) >> 10)   // 245 scan blocks

// ---------------- tiny zero fill (deg only; graph-capture-safe) ------------
__global__ void zero_int_kernel(int* __restrict__ p, int n) {
    int i = blockIdx.x * blockDim.x + threadIdx.x;
    if (i < n) p[i] = 0;
}

// ---------------- degree histogram -----------------------------------------
__global__ void hist_kernel(const int* __restrict__ erow, int* __restrict__ deg) {
    int e = blockIdx.x * 256 + threadIdx.x;
    if (e < NNZ) atomicAdd(&deg[erow[e]], 1);
}

// ---------------- exclusive scan of deg -> offs (3-kernel, 1024 elem/blk) --
__global__ __launch_bounds__(256) void scan1_kernel(const int* __restrict__ deg,
                                                    int* __restrict__ offs,
                                                    int* __restrict__ bsum) {
    __shared__ int lds[256];
    int t = threadIdx.x;
    int base = (blockIdx.x << 10) + (t << 2);
    int d0 = (base + 0 < NTOT) ? deg[base + 0] : 0;
    int d1 = (base + 1 < NTOT) ? deg[base + 1] : 0;
    int d2 = (base + 2 < NTOT) ? deg[base + 2] : 0;
    int d3 = (base + 3 < NTOT) ? deg[base + 3] : 0;
    int s = d0 + d1 + d2 + d3;
    lds[t] = s;
    __syncthreads();
    for (int off = 1; off < 256; off <<= 1) {
        int v = (t >= off) ? lds[t - off] : 0;
        __syncthreads();
        lds[t] += v;
        __syncthreads();
    }
    int excl = lds[t] - s;   // exclusive prefix within block
    if (base + 0 < NTOT) offs[base + 0] = excl;
    if (base + 1 < NTOT) offs[base + 1] = excl + d0;
    if (base + 2 < NTOT) offs[base + 2] = excl + d0 + d1;
    if (base + 3 < NTOT) offs[base + 3] = excl + d0 + d1 + d2;
    if (t == 255) bsum[blockIdx.x] = lds[255];
}

__global__ __launch_bounds__(256) void scan2_kernel(int* __restrict__ bsum) {
    __shared__ int lds[256];
    int t = threadIdx.x;
    int v0 = (t < NBLK1) ? bsum[t] : 0;
    lds[t] = v0;
    __syncthreads();
    for (int off = 1; off < 256; off <<= 1) {
        int v = (t >= off) ? lds[t - off] : 0;
        __syncthreads();
        lds[t] += v;
        __syncthreads();
    }
    if (t < NBLK1) bsum[t] = lds[t] - v0;   // exclusive
}

__global__ void scan3_kernel(int* __restrict__ offs, const int* __restrict__ bsum) {
    int i = blockIdx.x * 256 + threadIdx.x;
    if (i < NTOT) offs[i] += bsum[i >> 10];
    if (i == 0) offs[NTOT] = NNZ;
}

// ---------------- CSR fill: consume deg as countdown cursor ----------------
__global__ void fill_kernel(const int* __restrict__ erow, const int* __restrict__ ecol,
                            const float* __restrict__ eval_, const int* __restrict__ offs,
                            int* __restrict__ deg, int2* __restrict__ colval) {
    int e = blockIdx.x * 256 + threadIdx.x;
    if (e >= NNZ) return;
    int r = erow[e];
    int slot = atomicSub(&deg[r], 1) - 1;
    colval[offs[r] + slot] = make_int2(ecol[e], __float_as_int(eval_[e]));
}

// ---------------- GNN layer: wave per row, gather+accumulate+normalize -----
// srcEmb == nullptr -> read from concat(user,item)
__global__ __launch_bounds__(256) void layer_kernel(const float* __restrict__ user,
                                                    const float* __restrict__ item,
                                                    const float* __restrict__ srcEmb,
                                                    const int*  __restrict__ offs,
                                                    const int2* __restrict__ colval,
                                                    float* __restrict__ dst) {
    int row  = (blockIdx.x << 2) + (threadIdx.x >> 6);
    int lane = threadIdx.x & 63;
    if (row >= NTOT) return;
    int o0 = offs[row], o1 = offs[row + 1];
    float acc = 0.f;
    for (int i = o0; i < o1; ++i) {
        int2 cv = colval[i];
        float v = __int_as_float(cv.y);
        const float* src;
        if (srcEmb) src = srcEmb + (size_t)cv.x * D64;
        else        src = (cv.x < N_USER) ? user + (size_t)cv.x * D64
                                          : item + (size_t)(cv.x - N_USER) * D64;
        acc = fmaf(v, src[lane], acc);
    }
    float s = acc * acc;
    #pragma unroll
    for (int m = 32; m >= 1; m >>= 1) s += __shfl_xor(s, m, 64);
    float scale = 1.f / fmaxf(sqrtf(s), 1e-12f);
    dst[(size_t)row * D64 + lane] = acc * scale;
}

// ---------------- fused head: thread per batch element ---------------------
// No seq buffer: read source rows directly via node id. x/xs recomputed per-d
// to keep the live set ~210 VGPRs (no scratch spills).
__global__ __launch_bounds__(64, 1) void final_kernel(
    const int*   __restrict__ nids,
    const float* __restrict__ user,      const float* __restrict__ item,
    const float* __restrict__ embA,      const float* __restrict__ embB,
    const float* __restrict__ down_w,    const float* __restrict__ in_proj_w,
    const float* __restrict__ conv_w,    const float* __restrict__ conv_b,
    const float* __restrict__ x_proj_w,  const float* __restrict__ dt_proj_w,
    const float* __restrict__ dt_proj_b, const float* __restrict__ A_log,
    const float* __restrict__ D_param,   const float* __restrict__ out_proj_w,
    const float* __restrict__ ln_g,      const float* __restrict__ ln_b,
    const float* __restrict__ to_logit_w,const float* __restrict__ to_logit_b,
    float* __restrict__ out) {

    __shared__ float4 s_down4[GD * 16];     // down_w row-major, float4 chunks
    __shared__ float4 s_ipx4[DINNER * 4];   // in_proj rows 0..31 (x branch)
    __shared__ float4 s_ipz4[DINNER * 4];   // in_proj rows 32..63 (z branch)
    __shared__ float  s_xpT[DINNER * 17];   // x_proj transposed: [d][17]
    __shared__ float4 s_cw4[DINNER];        // conv_w per-channel
    __shared__ float  s_cb[DINNER];
    __shared__ float  s_dtw[DINNER], s_dtb[DINNER], s_Dp[DINNER];
    __shared__ float  s_A[DINNER * DSTATE]; // -exp(A_log), [d][8]
    __shared__ float4 s_opT4[DINNER * 4];   // out_proj transposed: [d][16]
    __shared__ float  s_lng[GD], s_lnb[GD], s_lw[GD];
    __shared__ float  s_lb;

    int t = threadIdx.x;
    {
        const float4* dw4 = (const float4*)down_w;
        for (int i = t; i < GD * 16; i += 64) s_down4[i] = dw4[i];
        const float4* ip4 = (const float4*)in_proj_w;
        for (int i = t; i < DINNER * 4; i += 64) { s_ipx4[i] = ip4[i]; s_ipz4[i] = ip4[DINNER * 4 + i]; }
        for (int i = t; i < DINNER * 17; i += 64) {
            int d = i / 17, r = i % 17;
            s_xpT[i] = x_proj_w[r * DINNER + d];
        }
        const float4* cw4 = (const float4*)conv_w;
        for (int i = t; i < DINNER; i += 64) {
            s_cw4[i] = cw4[i]; s_cb[i] = conv_b[i]; s_dtw[i] = dt_proj_w[i];
            s_dtb[i] = dt_proj_b[i]; s_Dp[i] = D_param[i];
        }
        for (int i = t; i < DINNER * DSTATE; i += 64) s_A[i] = -expf(A_log[i]);
        float* s_opT = (float*)s_opT4;
        for (int i = t; i < DINNER * GD; i += 64) {
            int d = i >> 4, j = i & 15;
            s_opT[i] = out_proj_w[j * DINNER + d];
        }
        if (t < GD) { s_lng[t] = ln_g[t]; s_lnb[t] = ln_b[t]; s_lw[t] = to_logit_w[t]; }
        if (t == 0) s_lb = to_logit_b[0];
    }
    __syncthreads();

    int b = blockIdx.x * 64 + t;
    int nid = nids[b];
    const float4* p0 = (const float4*)((nid < N_USER) ? user + (size_t)nid * D64
                                                      : item + (size_t)(nid - N_USER) * D64);
    const float4* p1 = (const float4*)(embA + (size_t)nid * D64);
    const float4* p2 = (const float4*)(embB + (size_t)nid * D64);

    // ---- g = seq @ down_w.T : (3,16); weight float4 reused across l ----
    float g[LSEQ][GD];
    #pragma unroll
    for (int l = 0; l < LSEQ; ++l)
        #pragma unroll
        for (int j = 0; j < GD; ++j) g[l][j] = 0.f;
    #pragma unroll
    for (int q = 0; q < 16; ++q) {
        float4 v0 = p0[q], v1 = p1[q], v2 = p2[q];
        #pragma unroll
        for (int j = 0; j < GD; ++j) {
            float4 w = s_down4[j * 16 + q];
            g[0][j] = fmaf(v0.x, w.x, fmaf(v0.y, w.y, fmaf(v0.z, w.z, fmaf(v0.w, w.w, g[0][j]))));
            g[1][j] = fmaf(v1.x, w.x, fmaf(v1.y, w.y, fmaf(v1.z, w.z, fmaf(v1.w, w.w, g[1][j]))));
            g[2][j] = fmaf(v2.x, w.x, fmaf(v2.y, w.y, fmaf(v2.z, w.z, fmaf(v2.w, w.w, g[2][j]))));
        }
    }

    // helper macro: compute xs0..xs2 (post-conv silu) for channel d
    #define COMPUTE_XS(d, xs0, xs1, xs2)                                          \
        float xs0, xs1, xs2;                                                      \
        {                                                                         \
            float xl0 = 0.f, xl1 = 0.f, xl2 = 0.f;                                \
            _Pragma("unroll")                                                     \
            for (int qq = 0; qq < 4; ++qq) {                                      \
                float4 w = s_ipx4[(d) * 4 + qq];                                  \
                xl0 = fmaf(g[0][4*qq+0], w.x, fmaf(g[0][4*qq+1], w.y,             \
                      fmaf(g[0][4*qq+2], w.z, fmaf(g[0][4*qq+3], w.w, xl0))));    \
                xl1 = fmaf(g[1][4*qq+0], w.x, fmaf(g[1][4*qq+1], w.y,             \
                      fmaf(g[1][4*qq+2], w.z, fmaf(g[1][4*qq+3], w.w, xl1))));    \
                xl2 = fmaf(g[2][4*qq+0], w.x, fmaf(g[2][4*qq+1], w.y,             \
                      fmaf(g[2][4*qq+2], w.z, fmaf(g[2][4*qq+3], w.w, xl2))));    \
            }                                                                     \
            float4 cw = s_cw4[d]; float cb = s_cb[d];                             \
            float a0 = fmaf(xl0, cw.w, cb);                                       \
            float a1 = fmaf(xl1, cw.w, fmaf(xl0, cw.z, cb));                      \
            float a2 = fmaf(xl2, cw.w, fmaf(xl1, cw.z, fmaf(xl0, cw.y, cb)));     \
            xs0 = a0 / (1.f + __expf(-a0));                                       \
            xs1 = a1 / (1.f + __expf(-a1));                                       \
            xs2 = a2 / (1.f + __expf(-a2));                                       \
        }

    // ---- pass 1 over d: accumulate dt_raw, B, C ----
    float dtr[LSEQ] = {0.f, 0.f, 0.f};
    float Bm[LSEQ][DSTATE], Cm[LSEQ][DSTATE];
    #pragma unroll
    for (int l = 0; l < LSEQ; ++l)
        #pragma unroll
        for (int s = 0; s < DSTATE; ++s) { Bm[l][s] = 0.f; Cm[l][s] = 0.f; }

    for (int d = 0; d < DINNER; ++d) {
        COMPUTE_XS(d, xs0, xs1, xs2)
        const float* xt = s_xpT + d * 17;
        float w = xt[0];
        dtr[0] = fmaf(xs0, w, dtr[0]); dtr[1] = fmaf(xs1, w, dtr[1]); dtr[2] = fmaf(xs2, w, dtr[2]);
        #pragma unroll
        for (int s = 0; s < DSTATE; ++s) {
            float wb = xt[1 + s], wc = xt[9 + s];
            Bm[0][s] = fmaf(xs0, wb, Bm[0][s]); Bm[1][s] = fmaf(xs1, wb, Bm[1][s]); Bm[2][s] = fmaf(xs2, wb, Bm[2][s]);
            Cm[0][s] = fmaf(xs0, wc, Cm[0][s]); Cm[1][s] = fmaf(xs1, wc, Cm[1][s]); Cm[2][s] = fmaf(xs2, wc, Cm[2][s]);
        }
    }

    // ---- pass 2 over d: selective scan fused with z-gate and out_proj ----
    float o[LSEQ][GD];
    #pragma unroll
    for (int l = 0; l < LSEQ; ++l)
        #pragma unroll
        for (int j = 0; j < GD; ++j) o[l][j] = 0.f;

    for (int d = 0; d < DINNER; ++d) {
        COMPUTE_XS(d, ys0, ys1, ys2)
        float xsv[3] = {ys0, ys1, ys2};
        float As[DSTATE];
        #pragma unroll
        for (int s = 0; s < DSTATE; ++s) As[s] = s_A[d * DSTATE + s];
        float dtw = s_dtw[d], dtb = s_dtb[d], Dp = s_Dp[d];
        float h[DSTATE];
        #pragma unroll
        for (int s = 0; s < DSTATE; ++s) h[s] = 0.f;
        #pragma unroll
        for (int l = 0; l < LSEQ; ++l) {
            float pre = fmaf(dtr[l], dtw, dtb);
            float dt  = (pre > 20.f) ? pre : __logf(1.f + __expf(pre));
            float xv  = xsv[l];
            float dtx = dt * xv;
            float acc = 0.f;
            #pragma unroll
            for (int s = 0; s < DSTATE; ++s) {
                float dA = __expf(dt * As[s]);
                h[s] = fmaf(dA, h[s], dtx * Bm[l][s]);
                acc  = fmaf(h[s], Cm[l][s], acc);
            }
            float y = fmaf(Dp, xv, acc);
            float zv = 0.f;
            #pragma unroll
            for (int qq = 0; qq < 4; ++qq) {
                float4 w = s_ipz4[d * 4 + qq];
                zv = fmaf(g[l][4*qq+0], w.x, fmaf(g[l][4*qq+1], w.y,
                     fmaf(g[l][4*qq+2], w.z, fmaf(g[l][4*qq+3], w.w, zv))));
            }
            float ys = y * (zv / (1.f + __expf(-zv)));
            #pragma unroll
            for (int qq = 0; qq < 4; ++qq) {
                float4 w = s_opT4[d * 4 + qq];
                o[l][4*qq+0] = fmaf(ys, w.x, o[l][4*qq+0]);
                o[l][4*qq+1] = fmaf(ys, w.y, o[l][4*qq+1]);
                o[l][4*qq+2] = fmaf(ys, w.z, o[l][4*qq+2]);
                o[l][4*qq+3] = fmaf(ys, w.w, o[l][4*qq+3]);
            }
        }
    }

    // ---- residual + LayerNorm(16) + logit + softmax(T=0.8) ----
    float lg[LSEQ];
    #pragma unroll
    for (int l = 0; l < LSEQ; ++l) {
        float mu = 0.f;
        #pragma unroll
        for (int j = 0; j < GD; ++j) { o[l][j] += g[l][j]; mu += o[l][j]; }
        mu *= (1.f / GD);
        float var = 0.f;
        #pragma unroll
        for (int j = 0; j < GD; ++j) { float dd = o[l][j] - mu; var = fmaf(dd, dd, var); }
        var *= (1.f / GD);
        float inv = rsqrtf(var + 1e-12f);
        float lo = 0.f;
        #pragma unroll
        for (int j = 0; j < GD; ++j)
            lo = fmaf(fmaf((o[l][j] - mu) * inv, s_lng[j], s_lnb[j]), s_lw[j], lo);
        lg[l] = (lo + s_lb) * (1.0f / 0.8f);
    }
    float mx = fmaxf(lg[0], fmaxf(lg[1], lg[2]));
    float e0 = __expf(lg[0] - mx), e1 = __expf(lg[1] - mx), e2 = __expf(lg[2] - mx);
    float inv = 1.f / (e0 + e1 + e2);
    float w0 = e0 * inv, w1 = e1 * inv, w2 = e2 * inv;

    // ---- fused = w0*seq0 + w1*seq1 + w2*seq2 (re-read rows, L2-hot) ----
    float4* o4 = (float4*)(out + (size_t)b * D64);
    #pragma unroll
    for (int q = 0; q < 16; ++q) {
        float4 a = p0[q], bb = p1[q], c = p2[q], r;
        r.x = w0 * a.x + w1 * bb.x + w2 * c.x;
        r.y = w0 * a.y + w1 * bb.y + w2 * c.y;
        r.z = w0 * a.z + w1 * bb.z + w2 * c.z;
        r.w = w0 * a.w + w1 * bb.w + w2 * c.w;
        o4[q] = r;
    }
}

extern "C" void kernel_launch(void* const* d_in, const int* in_sizes, int n_in,
                              void* d_out, int out_size, void* d_ws, size_t ws_size,
                              hipStream_t stream) {
    const float* user      = (const float*)d_in[0];
    const float* item      = (const float*)d_in[1];
    const int*   erow      = (const int*)  d_in[2];
    const int*   ecol      = (const int*)  d_in[3];
    const float* eval_     = (const float*)d_in[4];
    const int*   nids      = (const int*)  d_in[5];
    const float* down_w    = (const float*)d_in[6];
    const float* in_proj_w = (const float*)d_in[7];
    const float* conv_w    = (const float*)d_in[8];
    const float* conv_b    = (const float*)d_in[9];
    const float* x_proj_w  = (const float*)d_in[10];
    const float* dt_proj_w = (const float*)d_in[11];
    const float* dt_proj_b = (const float*)d_in[12];
    const float* A_log     = (const float*)d_in[13];
    const float* D_param   = (const float*)d_in[14];
    const float* out_projw = (const float*)d_in[15];
    const float* ln_g      = (const float*)d_in[16];
    const float* ln_b      = (const float*)d_in[17];
    const float* to_lw     = (const float*)d_in[18];
    const float* to_lb     = (const float*)d_in[19];
    float* out = (float*)d_out;

    // workspace layout (~140.0 MB total)
    char* base = (char*)d_ws;
    float* embA = (float*)base;                              // 64,000,000 B
    float* embB = (float*)(base + 64000000);                 // 64,000,000 B
    char* c = base + 128000000;
    int* offs = (int*)c;  c += (size_t)(NTOT + 1) * 4;       // 1,000,004 B
    int* deg  = (int*)c;  c += (size_t)NTOT * 4;             // 1,000,000 B
    int* bsum = (int*)c;  c += 1024;                         // scan block sums
    c = (char*)(((uintptr_t)c + 7) & ~(uintptr_t)7);
    int2* colval = (int2*)c;                                 // 10,000,000 B

    // ---- build CSR ----
    zero_int_kernel<<<(NTOT + 255) / 256, 256, 0, stream>>>(deg, NTOT);
    hist_kernel<<<(NNZ + 255) / 256, 256, 0, stream>>>(erow, deg);
    scan1_kernel<<<NBLK1, 256, 0, stream>>>(deg, offs, bsum);
    scan2_kernel<<<1, 256, 0, stream>>>(bsum);
    scan3_kernel<<<(NTOT + 255) / 256, 256, 0, stream>>>(offs, bsum);
    fill_kernel<<<(NNZ + 255) / 256, 256, 0, stream>>>(erow, ecol, eval_, offs, deg, colval);

    // ---- two GNN layers: gather-accumulate + fused normalize ----
    layer_kernel<<<NTOT / 4, 256, 0, stream>>>(user, item, nullptr, offs, colval, embA);
    layer_kernel<<<NTOT / 4, 256, 0, stream>>>(user, item, embA, offs, colval, embB);

    // ---- fused head ----
    final_kernel<<<BATCH / 64, 64, 0, stream>>>(nids, user, item, embA, embB,
                                                down_w, in_proj_w, conv_w, conv_b,
                                                x_proj_w, dt_proj_w, dt_proj_b, A_log,
                                                D_param, out_projw, ln_g, ln_b, to_lw, to_lb, out);
}

// Round 3
// 435.398 us; speedup vs baseline: 2.4257x; 1.4493x over previous
//
#include <hip/hip_runtime.h>
#include <math.h>

#define N_USER 100000
#define N_ITEM 150000
#define NTOT   250000
#define D64    64
#define NNZ    1250000
#define BATCH  16384
#define GD     16
#define DSTATE 8
#define DCONV  4
#define DINNER 32
#define LSEQ   3
#define NBLK1  ((NTOT + 1023) >> 10)   // 245 scan blocks

// ---------------- tiny zero fill (deg only; graph-capture-safe) ------------
__global__ void zero_int_kernel(int* __restrict__ p, int n) {
    int i = blockIdx.x * blockDim.x + threadIdx.x;
    if (i < n) p[i] = 0;
}

// ---------------- degree histogram -----------------------------------------
__global__ void hist_kernel(const int* __restrict__ erow, int* __restrict__ deg) {
    int e = blockIdx.x * 256 + threadIdx.x;
    if (e < NNZ) atomicAdd(&deg[erow[e]], 1);
}

// ---------------- exclusive scan of deg -> offs (3-kernel, 1024 elem/blk) --
__global__ __launch_bounds__(256) void scan1_kernel(const int* __restrict__ deg,
                                                    int* __restrict__ offs,
                                                    int* __restrict__ bsum) {
    __shared__ int lds[256];
    int t = threadIdx.x;
    int base = (blockIdx.x << 10) + (t << 2);
    int d0 = (base + 0 < NTOT) ? deg[base + 0] : 0;
    int d1 = (base + 1 < NTOT) ? deg[base + 1] : 0;
    int d2 = (base + 2 < NTOT) ? deg[base + 2] : 0;
    int d3 = (base + 3 < NTOT) ? deg[base + 3] : 0;
    int s = d0 + d1 + d2 + d3;
    lds[t] = s;
    __syncthreads();
    for (int off = 1; off < 256; off <<= 1) {
        int v = (t >= off) ? lds[t - off] : 0;
        __syncthreads();
        lds[t] += v;
        __syncthreads();
    }
    int excl = lds[t] - s;   // exclusive prefix within block
    if (base + 0 < NTOT) offs[base + 0] = excl;
    if (base + 1 < NTOT) offs[base + 1] = excl + d0;
    if (base + 2 < NTOT) offs[base + 2] = excl + d0 + d1;
    if (base + 3 < NTOT) offs[base + 3] = excl + d0 + d1 + d2;
    if (t == 255) bsum[blockIdx.x] = lds[255];
}

__global__ __launch_bounds__(256) void scan2_kernel(int* __restrict__ bsum) {
    __shared__ int lds[256];
    int t = threadIdx.x;
    int v0 = (t < NBLK1) ? bsum[t] : 0;
    lds[t] = v0;
    __syncthreads();
    for (int off = 1; off < 256; off <<= 1) {
        int v = (t >= off) ? lds[t - off] : 0;
        __syncthreads();
        lds[t] += v;
        __syncthreads();
    }
    if (t < NBLK1) bsum[t] = lds[t] - v0;   // exclusive
}

__global__ void scan3_kernel(int* __restrict__ offs, const int* __restrict__ bsum) {
    int i = blockIdx.x * 256 + threadIdx.x;
    if (i < NTOT) offs[i] += bsum[i >> 10];
    if (i == 0) offs[NTOT] = NNZ;
}

// ---------------- CSR fill: consume deg as countdown cursor ----------------
__global__ void fill_kernel(const int* __restrict__ erow, const int* __restrict__ ecol,
                            const float* __restrict__ eval_, const int* __restrict__ offs,
                            int* __restrict__ deg, int2* __restrict__ colval) {
    int e = blockIdx.x * 256 + threadIdx.x;
    if (e >= NNZ) return;
    int r = erow[e];
    int slot = atomicSub(&deg[r], 1) - 1;
    colval[offs[r] + slot] = make_int2(ecol[e], __float_as_int(eval_[e]));
}

// ---------------- GNN layer: quarter-wave (16 lanes x float4) per row ------
// Each lane owns 4 features exclusively -> accumulation stays in-register.
// 4 independent row chains per wave + edge-loop unroll x2 = up to 8
// outstanding 16B gathers per wave (vs 1 in the wave-per-row version).
// srcEmb == nullptr -> read from concat(user,item)
__global__ __launch_bounds__(256) void layer_kernel(const float* __restrict__ user,
                                                    const float* __restrict__ item,
                                                    const float* __restrict__ srcEmb,
                                                    const int*  __restrict__ offs,
                                                    const int2* __restrict__ colval,
                                                    float* __restrict__ dst) {
    const float4* user4 = (const float4*)user;
    const float4* item4 = (const float4*)item;
    const float4* src4  = (const float4*)srcEmb;

    int row    = (blockIdx.x << 4) + (threadIdx.x >> 4);  // 16 rows per block
    int lane16 = threadIdx.x & 15;                        // feature block (4 floats)
    if (row >= NTOT) return;
    int o0 = offs[row], o1 = offs[row + 1];

    float4 acc = make_float4(0.f, 0.f, 0.f, 0.f);
    int i = o0;
    for (; i + 2 <= o1; i += 2) {
        int2 cv0 = colval[i];
        int2 cv1 = colval[i + 1];
        const float4* s0;
        const float4* s1;
        if (srcEmb) {
            s0 = src4 + (size_t)cv0.x * 16;
            s1 = src4 + (size_t)cv1.x * 16;
        } else {
            s0 = (cv0.x < N_USER) ? user4 + (size_t)cv0.x * 16
                                  : item4 + (size_t)(cv0.x - N_USER) * 16;
            s1 = (cv1.x < N_USER) ? user4 + (size_t)cv1.x * 16
                                  : item4 + (size_t)(cv1.x - N_USER) * 16;
        }
        float4 v0 = s0[lane16];
        float4 v1 = s1[lane16];
        float w0 = __int_as_float(cv0.y);
        float w1 = __int_as_float(cv1.y);
        acc.x = fmaf(w1, v1.x, fmaf(w0, v0.x, acc.x));
        acc.y = fmaf(w1, v1.y, fmaf(w0, v0.y, acc.y));
        acc.z = fmaf(w1, v1.z, fmaf(w0, v0.z, acc.z));
        acc.w = fmaf(w1, v1.w, fmaf(w0, v0.w, acc.w));
    }
    if (i < o1) {
        int2 cv = colval[i];
        const float4* s0;
        if (srcEmb) s0 = src4 + (size_t)cv.x * 16;
        else        s0 = (cv.x < N_USER) ? user4 + (size_t)cv.x * 16
                                         : item4 + (size_t)(cv.x - N_USER) * 16;
        float4 v = s0[lane16];
        float w = __int_as_float(cv.y);
        acc.x = fmaf(w, v.x, acc.x);
        acc.y = fmaf(w, v.y, acc.y);
        acc.z = fmaf(w, v.z, acc.z);
        acc.w = fmaf(w, v.w, acc.w);
    }

    // L2 norm across the 16 lanes of this row (xor masks 1/2/4/8 stay in-group)
    float s = fmaf(acc.x, acc.x, fmaf(acc.y, acc.y, fmaf(acc.z, acc.z, acc.w * acc.w)));
    #pragma unroll
    for (int m = 8; m >= 1; m >>= 1) s += __shfl_xor(s, m, 64);
    float scale = 1.f / fmaxf(sqrtf(s), 1e-12f);
    float4 r;
    r.x = acc.x * scale; r.y = acc.y * scale; r.z = acc.z * scale; r.w = acc.w * scale;
    ((float4*)dst)[(size_t)row * 16 + lane16] = r;
}

// ---------------- fused head: thread per batch element ---------------------
__global__ __launch_bounds__(64, 1) void final_kernel(
    const int*   __restrict__ nids,
    const float* __restrict__ user,      const float* __restrict__ item,
    const float* __restrict__ embA,      const float* __restrict__ embB,
    const float* __restrict__ down_w,    const float* __restrict__ in_proj_w,
    const float* __restrict__ conv_w,    const float* __restrict__ conv_b,
    const float* __restrict__ x_proj_w,  const float* __restrict__ dt_proj_w,
    const float* __restrict__ dt_proj_b, const float* __restrict__ A_log,
    const float* __restrict__ D_param,   const float* __restrict__ out_proj_w,
    const float* __restrict__ ln_g,      const float* __restrict__ ln_b,
    const float* __restrict__ to_logit_w,const float* __restrict__ to_logit_b,
    float* __restrict__ out) {

    __shared__ float4 s_down4[GD * 16];     // down_w row-major, float4 chunks
    __shared__ float4 s_ipx4[DINNER * 4];   // in_proj rows 0..31 (x branch)
    __shared__ float4 s_ipz4[DINNER * 4];   // in_proj rows 32..63 (z branch)
    __shared__ float  s_xpT[DINNER * 17];   // x_proj transposed: [d][17]
    __shared__ float4 s_cw4[DINNER];        // conv_w per-channel
    __shared__ float  s_cb[DINNER];
    __shared__ float  s_dtw[DINNER], s_dtb[DINNER], s_Dp[DINNER];
    __shared__ float  s_A[DINNER * DSTATE]; // -exp(A_log), [d][8]
    __shared__ float4 s_opT4[DINNER * 4];   // out_proj transposed: [d][16]
    __shared__ float  s_lng[GD], s_lnb[GD], s_lw[GD];
    __shared__ float  s_lb;

    int t = threadIdx.x;
    {
        const float4* dw4 = (const float4*)down_w;
        for (int i = t; i < GD * 16; i += 64) s_down4[i] = dw4[i];
        const float4* ip4 = (const float4*)in_proj_w;
        for (int i = t; i < DINNER * 4; i += 64) { s_ipx4[i] = ip4[i]; s_ipz4[i] = ip4[DINNER * 4 + i]; }
        for (int i = t; i < DINNER * 17; i += 64) {
            int d = i / 17, r = i % 17;
            s_xpT[i] = x_proj_w[r * DINNER + d];
        }
        const float4* cw4 = (const float4*)conv_w;
        for (int i = t; i < DINNER; i += 64) {
            s_cw4[i] = cw4[i]; s_cb[i] = conv_b[i]; s_dtw[i] = dt_proj_w[i];
            s_dtb[i] = dt_proj_b[i]; s_Dp[i] = D_param[i];
        }
        for (int i = t; i < DINNER * DSTATE; i += 64) s_A[i] = -expf(A_log[i]);
        float* s_opT = (float*)s_opT4;
        for (int i = t; i < DINNER * GD; i += 64) {
            int d = i >> 4, j = i & 15;
            s_opT[i] = out_proj_w[j * DINNER + d];
        }
        if (t < GD) { s_lng[t] = ln_g[t]; s_lnb[t] = ln_b[t]; s_lw[t] = to_logit_w[t]; }
        if (t == 0) s_lb = to_logit_b[0];
    }
    __syncthreads();

    int b = blockIdx.x * 64 + t;
    int nid = nids[b];
    const float4* p0 = (const float4*)((nid < N_USER) ? user + (size_t)nid * D64
                                                      : item + (size_t)(nid - N_USER) * D64);
    const float4* p1 = (const float4*)(embA + (size_t)nid * D64);
    const float4* p2 = (const float4*)(embB + (size_t)nid * D64);

    // ---- g = seq @ down_w.T : (3,16); weight float4 reused across l ----
    float g[LSEQ][GD];
    #pragma unroll
    for (int l = 0; l < LSEQ; ++l)
        #pragma unroll
        for (int j = 0; j < GD; ++j) g[l][j] = 0.f;
    #pragma unroll
    for (int q = 0; q < 16; ++q) {
        float4 v0 = p0[q], v1 = p1[q], v2 = p2[q];
        #pragma unroll
        for (int j = 0; j < GD; ++j) {
            float4 w = s_down4[j * 16 + q];
            g[0][j] = fmaf(v0.x, w.x, fmaf(v0.y, w.y, fmaf(v0.z, w.z, fmaf(v0.w, w.w, g[0][j]))));
            g[1][j] = fmaf(v1.x, w.x, fmaf(v1.y, w.y, fmaf(v1.z, w.z, fmaf(v1.w, w.w, g[1][j]))));
            g[2][j] = fmaf(v2.x, w.x, fmaf(v2.y, w.y, fmaf(v2.z, w.z, fmaf(v2.w, w.w, g[2][j]))));
        }
    }

    // helper macro: compute xs0..xs2 (post-conv silu) for channel d
    #define COMPUTE_XS(d, xs0, xs1, xs2)                                          \
        float xs0, xs1, xs2;                                                      \
        {                                                                         \
            float xl0 = 0.f, xl1 = 0.f, xl2 = 0.f;                                \
            _Pragma("unroll")                                                     \
            for (int qq = 0; qq < 4; ++qq) {                                      \
                float4 w = s_ipx4[(d) * 4 + qq];                                  \
                xl0 = fmaf(g[0][4*qq+0], w.x, fmaf(g[0][4*qq+1], w.y,             \
                      fmaf(g[0][4*qq+2], w.z, fmaf(g[0][4*qq+3], w.w, xl0))));    \
                xl1 = fmaf(g[1][4*qq+0], w.x, fmaf(g[1][4*qq+1], w.y,             \
                      fmaf(g[1][4*qq+2], w.z, fmaf(g[1][4*qq+3], w.w, xl1))));    \
                xl2 = fmaf(g[2][4*qq+0], w.x, fmaf(g[2][4*qq+1], w.y,             \
                      fmaf(g[2][4*qq+2], w.z, fmaf(g[2][4*qq+3], w.w, xl2))));    \
            }                                                                     \
            float4 cw = s_cw4[d]; float cb = s_cb[d];                             \
            float a0 = fmaf(xl0, cw.w, cb);                                       \
            float a1 = fmaf(xl1, cw.w, fmaf(xl0, cw.z, cb));                      \
            float a2 = fmaf(xl2, cw.w, fmaf(xl1, cw.z, fmaf(xl0, cw.y, cb)));     \
            xs0 = a0 / (1.f + __expf(-a0));                                       \
            xs1 = a1 / (1.f + __expf(-a1));                                       \
            xs2 = a2 / (1.f + __expf(-a2));                                       \
        }

    // ---- pass 1 over d: accumulate dt_raw, B, C ----
    float dtr[LSEQ] = {0.f, 0.f, 0.f};
    float Bm[LSEQ][DSTATE], Cm[LSEQ][DSTATE];
    #pragma unroll
    for (int l = 0; l < LSEQ; ++l)
        #pragma unroll
        for (int s = 0; s < DSTATE; ++s) { Bm[l][s] = 0.f; Cm[l][s] = 0.f; }

    for (int d = 0; d < DINNER; ++d) {
        COMPUTE_XS(d, xs0, xs1, xs2)
        const float* xt = s_xpT + d * 17;
        float w = xt[0];
        dtr[0] = fmaf(xs0, w, dtr[0]); dtr[1] = fmaf(xs1, w, dtr[1]); dtr[2] = fmaf(xs2, w, dtr[2]);
        #pragma unroll
        for (int s = 0; s < DSTATE; ++s) {
            float wb = xt[1 + s], wc = xt[9 + s];
            Bm[0][s] = fmaf(xs0, wb, Bm[0][s]); Bm[1][s] = fmaf(xs1, wb, Bm[1][s]); Bm[2][s] = fmaf(xs2, wb, Bm[2][s]);
            Cm[0][s] = fmaf(xs0, wc, Cm[0][s]); Cm[1][s] = fmaf(xs1, wc, Cm[1][s]); Cm[2][s] = fmaf(xs2, wc, Cm[2][s]);
        }
    }

    // ---- pass 2 over d: selective scan fused with z-gate and out_proj ----
    float o[LSEQ][GD];
    #pragma unroll
    for (int l = 0; l < LSEQ; ++l)
        #pragma unroll
        for (int j = 0; j < GD; ++j) o[l][j] = 0.f;

    for (int d = 0; d < DINNER; ++d) {
        COMPUTE_XS(d, ys0, ys1, ys2)
        float xsv[3] = {ys0, ys1, ys2};
        float As[DSTATE];
        #pragma unroll
        for (int s = 0; s < DSTATE; ++s) As[s] = s_A[d * DSTATE + s];
        float dtw = s_dtw[d], dtb = s_dtb[d], Dp = s_Dp[d];
        float h[DSTATE];
        #pragma unroll
        for (int s = 0; s < DSTATE; ++s) h[s] = 0.f;
        #pragma unroll
        for (int l = 0; l < LSEQ; ++l) {
            float pre = fmaf(dtr[l], dtw, dtb);
            float dt  = (pre > 20.f) ? pre : __logf(1.f + __expf(pre));
            float xv  = xsv[l];
            float dtx = dt * xv;
            float acc = 0.f;
            #pragma unroll
            for (int s = 0; s < DSTATE; ++s) {
                float dA = __expf(dt * As[s]);
                h[s] = fmaf(dA, h[s], dtx * Bm[l][s]);
                acc  = fmaf(h[s], Cm[l][s], acc);
            }
            float y = fmaf(Dp, xv, acc);
            float zv = 0.f;
            #pragma unroll
            for (int qq = 0; qq < 4; ++qq) {
                float4 w = s_ipz4[d * 4 + qq];
                zv = fmaf(g[l][4*qq+0], w.x, fmaf(g[l][4*qq+1], w.y,
                     fmaf(g[l][4*qq+2], w.z, fmaf(g[l][4*qq+3], w.w, zv))));
            }
            float ys = y * (zv / (1.f + __expf(-zv)));
            #pragma unroll
            for (int qq = 0; qq < 4; ++qq) {
                float4 w = s_opT4[d * 4 + qq];
                o[l][4*qq+0] = fmaf(ys, w.x, o[l][4*qq+0]);
                o[l][4*qq+1] = fmaf(ys, w.y, o[l][4*qq+1]);
                o[l][4*qq+2] = fmaf(ys, w.z, o[l][4*qq+2]);
                o[l][4*qq+3] = fmaf(ys, w.w, o[l][4*qq+3]);
            }
        }
    }

    // ---- residual + LayerNorm(16) + logit + softmax(T=0.8) ----
    float lg[LSEQ];
    #pragma unroll
    for (int l = 0; l < LSEQ; ++l) {
        float mu = 0.f;
        #pragma unroll
        for (int j = 0; j < GD; ++j) { o[l][j] += g[l][j]; mu += o[l][j]; }
        mu *= (1.f / GD);
        float var = 0.f;
        #pragma unroll
        for (int j = 0; j < GD; ++j) { float dd = o[l][j] - mu; var = fmaf(dd, dd, var); }
        var *= (1.f / GD);
        float inv = rsqrtf(var + 1e-12f);
        float lo = 0.f;
        #pragma unroll
        for (int j = 0; j < GD; ++j)
            lo = fmaf(fmaf((o[l][j] - mu) * inv, s_lng[j], s_lnb[j]), s_lw[j], lo);
        lg[l] = (lo + s_lb) * (1.0f / 0.8f);
    }
    float mx = fmaxf(lg[0], fmaxf(lg[1], lg[2]));
    float e0 = __expf(lg[0] - mx), e1 = __expf(lg[1] - mx), e2 = __expf(lg[2] - mx);
    float inv = 1.f / (e0 + e1 + e2);
    float w0 = e0 * inv, w1 = e1 * inv, w2 = e2 * inv;

    // ---- fused = w0*seq0 + w1*seq1 + w2*seq2 (re-read rows, L2-hot) ----
    float4* o4 = (float4*)(out + (size_t)b * D64);
    #pragma unroll
    for (int q = 0; q < 16; ++q) {
        float4 a = p0[q], bb = p1[q], c = p2[q], r;
        r.x = w0 * a.x + w1 * bb.x + w2 * c.x;
        r.y = w0 * a.y + w1 * bb.y + w2 * c.y;
        r.z = w0 * a.z + w1 * bb.z + w2 * c.z;
        r.w = w0 * a.w + w1 * bb.w + w2 * c.w;
        o4[q] = r;
    }
}

extern "C" void kernel_launch(void* const* d_in, const int* in_sizes, int n_in,
                              void* d_out, int out_size, void* d_ws, size_t ws_size,
                              hipStream_t stream) {
    const float* user      = (const float*)d_in[0];
    const float* item      = (const float*)d_in[1];
    const int*   erow      = (const int*)  d_in[2];
    const int*   ecol      = (const int*)  d_in[3];
    const float* eval_     = (const float*)d_in[4];
    const int*   nids      = (const int*)  d_in[5];
    const float* down_w    = (const float*)d_in[6];
    const float* in_proj_w = (const float*)d_in[7];
    const float* conv_w    = (const float*)d_in[8];
    const float* conv_b    = (const float*)d_in[9];
    const float* x_proj_w  = (const float*)d_in[10];
    const float* dt_proj_w = (const float*)d_in[11];
    const float* dt_proj_b = (const float*)d_in[12];
    const float* A_log     = (const float*)d_in[13];
    const float* D_param   = (const float*)d_in[14];
    const float* out_projw = (const float*)d_in[15];
    const float* ln_g      = (const float*)d_in[16];
    const float* ln_b      = (const float*)d_in[17];
    const float* to_lw     = (const float*)d_in[18];
    const float* to_lb     = (const float*)d_in[19];
    float* out = (float*)d_out;

    // workspace layout (~140.0 MB total)
    char* base = (char*)d_ws;
    float* embA = (float*)base;                              // 64,000,000 B
    float* embB = (float*)(base + 64000000);                 // 64,000,000 B
    char* c = base + 128000000;
    int* offs = (int*)c;  c += (size_t)(NTOT + 1) * 4;       // 1,000,004 B
    int* deg  = (int*)c;  c += (size_t)NTOT * 4;             // 1,000,000 B
    int* bsum = (int*)c;  c += 1024;                         // scan block sums
    c = (char*)(((uintptr_t)c + 7) & ~(uintptr_t)7);
    int2* colval = (int2*)c;                                 // 10,000,000 B

    // ---- build CSR ----
    zero_int_kernel<<<(NTOT + 255) / 256, 256, 0, stream>>>(deg, NTOT);
    hist_kernel<<<(NNZ + 255) / 256, 256, 0, stream>>>(erow, deg);
    scan1_kernel<<<NBLK1, 256, 0, stream>>>(deg, offs, bsum);
    scan2_kernel<<<1, 256, 0, stream>>>(bsum);
    scan3_kernel<<<(NTOT + 255) / 256, 256, 0, stream>>>(offs, bsum);
    fill_kernel<<<(NNZ + 255) / 256, 256, 0, stream>>>(erow, ecol, eval_, offs, deg, colval);

    // ---- two GNN layers: gather-accumulate + fused normalize ----
    layer_kernel<<<NTOT / 16, 256, 0, stream>>>(user, item, nullptr, offs, colval, embA);
    layer_kernel<<<NTOT / 16, 256, 0, stream>>>(user, item, embA, offs, colval, embB);

    // ---- fused head ----
    final_kernel<<<BATCH / 64, 64, 0, stream>>>(nids, user, item, embA, embB,
                                                down_w, in_proj_w, conv_w, conv_b,
                                                x_proj_w, dt_proj_w, dt_proj_b, A_log,
                                                D_param, out_projw, ln_g, ln_b, to_lw, to_lb, out);
}

// Round 4
// 291.045 us; speedup vs baseline: 3.6288x; 1.4960x over previous
//
#include <hip/hip_runtime.h>
#include <math.h>

#define N_USER 100000
#define N_ITEM 150000
#define NTOT   250000
#define D64    64
#define NNZ    1250000
#define BATCH  16384
#define GD     16
#define DSTATE 8
#define DCONV  4
#define DINNER 32
#define LSEQ   3
#define NBLK1  ((NTOT + 1023) >> 10)   // 245 scan blocks

// ---------------- zero fill for cnt+flags region (int4-wide) ---------------
__global__ void zero4_kernel(int4* __restrict__ p, int n4) {
    int i = blockIdx.x * blockDim.x + threadIdx.x;
    if (i < n4) p[i] = make_int4(0, 0, 0, 0);
}

// ---------------- mark node_ids rows ---------------------------------------
__global__ void mark_nids_kernel(const int* __restrict__ nids,
                                 unsigned char* __restrict__ nidf,
                                 unsigned char* __restrict__ needf) {
    int b = blockIdx.x * 256 + threadIdx.x;
    if (b < BATCH) { int r = nids[b]; nidf[r] = 1; needf[r] = 1; }
}

// ---------------- mark cols needed as layer-2 sources ----------------------
__global__ void mark_need_kernel(const int* __restrict__ erow,
                                 const int* __restrict__ ecol,
                                 const unsigned char* __restrict__ nidf,
                                 unsigned char* __restrict__ needf) {
    int e = blockIdx.x * 256 + threadIdx.x;
    if (e < NNZ && nidf[erow[e]]) needf[ecol[e]] = 1;
}

// ---------------- histogram + slot assignment (needed edges only) ----------
__global__ void hist_slot_kernel(const int* __restrict__ erow,
                                 const unsigned char* __restrict__ needf,
                                 int* __restrict__ cnt, int* __restrict__ slot) {
    int e = blockIdx.x * 256 + threadIdx.x;
    if (e >= NNZ) return;
    int r = erow[e];
    if (needf[r]) slot[e] = atomicAdd(&cnt[r], 1);
}

// ---------------- exclusive scan of cnt -> offs (3-kernel) -----------------
__global__ __launch_bounds__(256) void scan1_kernel(const int* __restrict__ cnt,
                                                    int* __restrict__ offs,
                                                    int* __restrict__ bsum) {
    __shared__ int lds[256];
    int t = threadIdx.x;
    int base = (blockIdx.x << 10) + (t << 2);
    int d0 = (base + 0 < NTOT) ? cnt[base + 0] : 0;
    int d1 = (base + 1 < NTOT) ? cnt[base + 1] : 0;
    int d2 = (base + 2 < NTOT) ? cnt[base + 2] : 0;
    int d3 = (base + 3 < NTOT) ? cnt[base + 3] : 0;
    int s = d0 + d1 + d2 + d3;
    lds[t] = s;
    __syncthreads();
    for (int off = 1; off < 256; off <<= 1) {
        int v = (t >= off) ? lds[t - off] : 0;
        __syncthreads();
        lds[t] += v;
        __syncthreads();
    }
    int excl = lds[t] - s;
    if (base + 0 < NTOT) offs[base + 0] = excl;
    if (base + 1 < NTOT) offs[base + 1] = excl + d0;
    if (base + 2 < NTOT) offs[base + 2] = excl + d0 + d1;
    if (base + 3 < NTOT) offs[base + 3] = excl + d0 + d1 + d2;
    if (t == 255) bsum[blockIdx.x] = lds[255];
}

__global__ __launch_bounds__(256) void scan2_kernel(int* __restrict__ bsum) {
    __shared__ int lds[256];
    int t = threadIdx.x;
    int v0 = (t < NBLK1) ? bsum[t] : 0;
    lds[t] = v0;
    __syncthreads();
    for (int off = 1; off < 256; off <<= 1) {
        int v = (t >= off) ? lds[t - off] : 0;
        __syncthreads();
        lds[t] += v;
        __syncthreads();
    }
    if (t < NBLK1) bsum[t] = lds[t] - v0;
}

__global__ void scan3_kernel(int* __restrict__ offs, const int* __restrict__ bsum,
                             const int* __restrict__ cnt) {
    int i = blockIdx.x * 256 + threadIdx.x;
    if (i >= NTOT) return;
    int v = offs[i] + bsum[i >> 10];
    offs[i] = v;
    if (i == NTOT - 1) offs[NTOT] = v + cnt[i];   // true total (needed edges only)
}

// ---------------- CSR fill: atomic-free, needed edges only -----------------
__global__ void fill_kernel(const int* __restrict__ erow, const int* __restrict__ ecol,
                            const float* __restrict__ eval_, const int* __restrict__ offs,
                            const int* __restrict__ slot,
                            const unsigned char* __restrict__ needf,
                            int2* __restrict__ colval) {
    int e = blockIdx.x * 256 + threadIdx.x;
    if (e >= NNZ) return;
    int r = erow[e];
    if (!needf[r]) return;
    colval[offs[r] + slot[e]] = make_int2(ecol[e], __float_as_int(eval_[e]));
}

// ---------------- layer 1: quarter-wave per row, needed rows only ----------
__global__ __launch_bounds__(256) void layer1_kernel(const float* __restrict__ user,
                                                     const float* __restrict__ item,
                                                     const unsigned char* __restrict__ needf,
                                                     const int*  __restrict__ offs,
                                                     const int2* __restrict__ colval,
                                                     float* __restrict__ dst) {
    const float4* user4 = (const float4*)user;
    const float4* item4 = (const float4*)item;

    int row    = (blockIdx.x << 4) + (threadIdx.x >> 4);
    int lane16 = threadIdx.x & 15;
    if (row >= NTOT) return;
    if (!needf[row]) return;
    int o0 = offs[row], o1 = offs[row + 1];

    float4 acc = make_float4(0.f, 0.f, 0.f, 0.f);
    int i = o0;
    for (; i + 2 <= o1; i += 2) {
        int2 cv0 = colval[i];
        int2 cv1 = colval[i + 1];
        const float4* s0 = (cv0.x < N_USER) ? user4 + (size_t)cv0.x * 16
                                            : item4 + (size_t)(cv0.x - N_USER) * 16;
        const float4* s1 = (cv1.x < N_USER) ? user4 + (size_t)cv1.x * 16
                                            : item4 + (size_t)(cv1.x - N_USER) * 16;
        float4 v0 = s0[lane16];
        float4 v1 = s1[lane16];
        float w0 = __int_as_float(cv0.y);
        float w1 = __int_as_float(cv1.y);
        acc.x = fmaf(w1, v1.x, fmaf(w0, v0.x, acc.x));
        acc.y = fmaf(w1, v1.y, fmaf(w0, v0.y, acc.y));
        acc.z = fmaf(w1, v1.z, fmaf(w0, v0.z, acc.z));
        acc.w = fmaf(w1, v1.w, fmaf(w0, v0.w, acc.w));
    }
    if (i < o1) {
        int2 cv = colval[i];
        const float4* s0 = (cv.x < N_USER) ? user4 + (size_t)cv.x * 16
                                           : item4 + (size_t)(cv.x - N_USER) * 16;
        float4 v = s0[lane16];
        float w = __int_as_float(cv.y);
        acc.x = fmaf(w, v.x, acc.x);
        acc.y = fmaf(w, v.y, acc.y);
        acc.z = fmaf(w, v.z, acc.z);
        acc.w = fmaf(w, v.w, acc.w);
    }

    float s = fmaf(acc.x, acc.x, fmaf(acc.y, acc.y, fmaf(acc.z, acc.z, acc.w * acc.w)));
    #pragma unroll
    for (int m = 8; m >= 1; m >>= 1) s += __shfl_xor(s, m, 64);
    float scale = 1.f / fmaxf(sqrtf(s), 1e-12f);
    float4 r;
    r.x = acc.x * scale; r.y = acc.y * scale; r.z = acc.z * scale; r.w = acc.w * scale;
    ((float4*)dst)[(size_t)row * 16 + lane16] = r;
}

// ---------------- layer 2: only node_ids rows, compact output --------------
__global__ __launch_bounds__(256) void layer2_kernel(const float* __restrict__ embA,
                                                     const int*  __restrict__ nids,
                                                     const int*  __restrict__ offs,
                                                     const int2* __restrict__ colval,
                                                     float* __restrict__ embBc) {
    const float4* src4 = (const float4*)embA;
    int idx    = (blockIdx.x << 4) + (threadIdx.x >> 4);   // batch index
    int lane16 = threadIdx.x & 15;
    if (idx >= BATCH) return;
    int row = nids[idx];
    int o0 = offs[row], o1 = offs[row + 1];

    float4 acc = make_float4(0.f, 0.f, 0.f, 0.f);
    int i = o0;
    for (; i + 2 <= o1; i += 2) {
        int2 cv0 = colval[i];
        int2 cv1 = colval[i + 1];
        float4 v0 = src4[(size_t)cv0.x * 16 + lane16];
        float4 v1 = src4[(size_t)cv1.x * 16 + lane16];
        float w0 = __int_as_float(cv0.y);
        float w1 = __int_as_float(cv1.y);
        acc.x = fmaf(w1, v1.x, fmaf(w0, v0.x, acc.x));
        acc.y = fmaf(w1, v1.y, fmaf(w0, v0.y, acc.y));
        acc.z = fmaf(w1, v1.z, fmaf(w0, v0.z, acc.z));
        acc.w = fmaf(w1, v1.w, fmaf(w0, v0.w, acc.w));
    }
    if (i < o1) {
        int2 cv = colval[i];
        float4 v = src4[(size_t)cv.x * 16 + lane16];
        float w = __int_as_float(cv.y);
        acc.x = fmaf(w, v.x, acc.x);
        acc.y = fmaf(w, v.y, acc.y);
        acc.z = fmaf(w, v.z, acc.z);
        acc.w = fmaf(w, v.w, acc.w);
    }

    float s = fmaf(acc.x, acc.x, fmaf(acc.y, acc.y, fmaf(acc.z, acc.z, acc.w * acc.w)));
    #pragma unroll
    for (int m = 8; m >= 1; m >>= 1) s += __shfl_xor(s, m, 64);
    float scale = 1.f / fmaxf(sqrtf(s), 1e-12f);
    float4 r;
    r.x = acc.x * scale; r.y = acc.y * scale; r.z = acc.z * scale; r.w = acc.w * scale;
    ((float4*)embBc)[(size_t)idx * 16 + lane16] = r;
}

// ---------------- fused head: thread per batch element ---------------------
__global__ __launch_bounds__(64, 1) void final_kernel(
    const int*   __restrict__ nids,
    const float* __restrict__ user,      const float* __restrict__ item,
    const float* __restrict__ embA,      const float* __restrict__ embBc,
    const float* __restrict__ down_w,    const float* __restrict__ in_proj_w,
    const float* __restrict__ conv_w,    const float* __restrict__ conv_b,
    const float* __restrict__ x_proj_w,  const float* __restrict__ dt_proj_w,
    const float* __restrict__ dt_proj_b, const float* __restrict__ A_log,
    const float* __restrict__ D_param,   const float* __restrict__ out_proj_w,
    const float* __restrict__ ln_g,      const float* __restrict__ ln_b,
    const float* __restrict__ to_logit_w,const float* __restrict__ to_logit_b,
    float* __restrict__ out) {

    __shared__ float4 s_down4[GD * 16];
    __shared__ float4 s_ipx4[DINNER * 4];
    __shared__ float4 s_ipz4[DINNER * 4];
    __shared__ float  s_xpT[DINNER * 17];
    __shared__ float4 s_cw4[DINNER];
    __shared__ float  s_cb[DINNER];
    __shared__ float  s_dtw[DINNER], s_dtb[DINNER], s_Dp[DINNER];
    __shared__ float  s_A[DINNER * DSTATE];
    __shared__ float4 s_opT4[DINNER * 4];
    __shared__ float  s_lng[GD], s_lnb[GD], s_lw[GD];
    __shared__ float  s_lb;

    int t = threadIdx.x;
    {
        const float4* dw4 = (const float4*)down_w;
        for (int i = t; i < GD * 16; i += 64) s_down4[i] = dw4[i];
        const float4* ip4 = (const float4*)in_proj_w;
        for (int i = t; i < DINNER * 4; i += 64) { s_ipx4[i] = ip4[i]; s_ipz4[i] = ip4[DINNER * 4 + i]; }
        for (int i = t; i < DINNER * 17; i += 64) {
            int d = i / 17, r = i % 17;
            s_xpT[i] = x_proj_w[r * DINNER + d];
        }
        const float4* cw4 = (const float4*)conv_w;
        for (int i = t; i < DINNER; i += 64) {
            s_cw4[i] = cw4[i]; s_cb[i] = conv_b[i]; s_dtw[i] = dt_proj_w[i];
            s_dtb[i] = dt_proj_b[i]; s_Dp[i] = D_param[i];
        }
        for (int i = t; i < DINNER * DSTATE; i += 64) s_A[i] = -expf(A_log[i]);
        float* s_opT = (float*)s_opT4;
        for (int i = t; i < DINNER * GD; i += 64) {
            int d = i >> 4, j = i & 15;
            s_opT[i] = out_proj_w[j * DINNER + d];
        }
        if (t < GD) { s_lng[t] = ln_g[t]; s_lnb[t] = ln_b[t]; s_lw[t] = to_logit_w[t]; }
        if (t == 0) s_lb = to_logit_b[0];
    }
    __syncthreads();

    int b = blockIdx.x * 64 + t;
    int nid = nids[b];
    const float4* p0 = (const float4*)((nid < N_USER) ? user + (size_t)nid * D64
                                                      : item + (size_t)(nid - N_USER) * D64);
    const float4* p1 = (const float4*)(embA + (size_t)nid * D64);
    const float4* p2 = (const float4*)(embBc + (size_t)b * D64);

    float g[LSEQ][GD];
    #pragma unroll
    for (int l = 0; l < LSEQ; ++l)
        #pragma unroll
        for (int j = 0; j < GD; ++j) g[l][j] = 0.f;
    #pragma unroll
    for (int q = 0; q < 16; ++q) {
        float4 v0 = p0[q], v1 = p1[q], v2 = p2[q];
        #pragma unroll
        for (int j = 0; j < GD; ++j) {
            float4 w = s_down4[j * 16 + q];
            g[0][j] = fmaf(v0.x, w.x, fmaf(v0.y, w.y, fmaf(v0.z, w.z, fmaf(v0.w, w.w, g[0][j]))));
            g[1][j] = fmaf(v1.x, w.x, fmaf(v1.y, w.y, fmaf(v1.z, w.z, fmaf(v1.w, w.w, g[1][j]))));
            g[2][j] = fmaf(v2.x, w.x, fmaf(v2.y, w.y, fmaf(v2.z, w.z, fmaf(v2.w, w.w, g[2][j]))));
        }
    }

    #define COMPUTE_XS(d, xs0, xs1, xs2)                                          \
        float xs0, xs1, xs2;                                                      \
        {                                                                         \
            float xl0 = 0.f, xl1 = 0.f, xl2 = 0.f;                                \
            _Pragma("unroll")                                                     \
            for (int qq = 0; qq < 4; ++qq) {                                      \
                float4 w = s_ipx4[(d) * 4 + qq];                                  \
                xl0 = fmaf(g[0][4*qq+0], w.x, fmaf(g[0][4*qq+1], w.y,             \
                      fmaf(g[0][4*qq+2], w.z, fmaf(g[0][4*qq+3], w.w, xl0))));    \
                xl1 = fmaf(g[1][4*qq+0], w.x, fmaf(g[1][4*qq+1], w.y,             \
                      fmaf(g[1][4*qq+2], w.z, fmaf(g[1][4*qq+3], w.w, xl1))));    \
                xl2 = fmaf(g[2][4*qq+0], w.x, fmaf(g[2][4*qq+1], w.y,             \
                      fmaf(g[2][4*qq+2], w.z, fmaf(g[2][4*qq+3], w.w, xl2))));    \
            }                                                                     \
            float4 cw = s_cw4[d]; float cb = s_cb[d];                             \
            float a0 = fmaf(xl0, cw.w, cb);                                       \
            float a1 = fmaf(xl1, cw.w, fmaf(xl0, cw.z, cb));                      \
            float a2 = fmaf(xl2, cw.w, fmaf(xl1, cw.z, fmaf(xl0, cw.y, cb)));     \
            xs0 = a0 / (1.f + __expf(-a0));                                       \
            xs1 = a1 / (1.f + __expf(-a1));                                       \
            xs2 = a2 / (1.f + __expf(-a2));                                       \
        }

    float dtr[LSEQ] = {0.f, 0.f, 0.f};
    float Bm[LSEQ][DSTATE], Cm[LSEQ][DSTATE];
    #pragma unroll
    for (int l = 0; l < LSEQ; ++l)
        #pragma unroll
        for (int s = 0; s < DSTATE; ++s) { Bm[l][s] = 0.f; Cm[l][s] = 0.f; }

    for (int d = 0; d < DINNER; ++d) {
        COMPUTE_XS(d, xs0, xs1, xs2)
        const float* xt = s_xpT + d * 17;
        float w = xt[0];
        dtr[0] = fmaf(xs0, w, dtr[0]); dtr[1] = fmaf(xs1, w, dtr[1]); dtr[2] = fmaf(xs2, w, dtr[2]);
        #pragma unroll
        for (int s = 0; s < DSTATE; ++s) {
            float wb = xt[1 + s], wc = xt[9 + s];
            Bm[0][s] = fmaf(xs0, wb, Bm[0][s]); Bm[1][s] = fmaf(xs1, wb, Bm[1][s]); Bm[2][s] = fmaf(xs2, wb, Bm[2][s]);
            Cm[0][s] = fmaf(xs0, wc, Cm[0][s]); Cm[1][s] = fmaf(xs1, wc, Cm[1][s]); Cm[2][s] = fmaf(xs2, wc, Cm[2][s]);
        }
    }

    float o[LSEQ][GD];
    #pragma unroll
    for (int l = 0; l < LSEQ; ++l)
        #pragma unroll
        for (int j = 0; j < GD; ++j) o[l][j] = 0.f;

    for (int d = 0; d < DINNER; ++d) {
        COMPUTE_XS(d, ys0, ys1, ys2)
        float xsv[3] = {ys0, ys1, ys2};
        float As[DSTATE];
        #pragma unroll
        for (int s = 0; s < DSTATE; ++s) As[s] = s_A[d * DSTATE + s];
        float dtw = s_dtw[d], dtb = s_dtb[d], Dp = s_Dp[d];
        float h[DSTATE];
        #pragma unroll
        for (int s = 0; s < DSTATE; ++s) h[s] = 0.f;
        #pragma unroll
        for (int l = 0; l < LSEQ; ++l) {
            float pre = fmaf(dtr[l], dtw, dtb);
            float dt  = (pre > 20.f) ? pre : __logf(1.f + __expf(pre));
            float xv  = xsv[l];
            float dtx = dt * xv;
            float acc = 0.f;
            #pragma unroll
            for (int s = 0; s < DSTATE; ++s) {
                float dA = __expf(dt * As[s]);
                h[s] = fmaf(dA, h[s], dtx * Bm[l][s]);
                acc  = fmaf(h[s], Cm[l][s], acc);
            }
            float y = fmaf(Dp, xv, acc);
            float zv = 0.f;
            #pragma unroll
            for (int qq = 0; qq < 4; ++qq) {
                float4 w = s_ipz4[d * 4 + qq];
                zv = fmaf(g[l][4*qq+0], w.x, fmaf(g[l][4*qq+1], w.y,
                     fmaf(g[l][4*qq+2], w.z, fmaf(g[l][4*qq+3], w.w, zv))));
            }
            float ys = y * (zv / (1.f + __expf(-zv)));
            #pragma unroll
            for (int qq = 0; qq < 4; ++qq) {
                float4 w = s_opT4[d * 4 + qq];
                o[l][4*qq+0] = fmaf(ys, w.x, o[l][4*qq+0]);
                o[l][4*qq+1] = fmaf(ys, w.y, o[l][4*qq+1]);
                o[l][4*qq+2] = fmaf(ys, w.z, o[l][4*qq+2]);
                o[l][4*qq+3] = fmaf(ys, w.w, o[l][4*qq+3]);
            }
        }
    }

    float lg[LSEQ];
    #pragma unroll
    for (int l = 0; l < LSEQ; ++l) {
        float mu = 0.f;
        #pragma unroll
        for (int j = 0; j < GD; ++j) { o[l][j] += g[l][j]; mu += o[l][j]; }
        mu *= (1.f / GD);
        float var = 0.f;
        #pragma unroll
        for (int j = 0; j < GD; ++j) { float dd = o[l][j] - mu; var = fmaf(dd, dd, var); }
        var *= (1.f / GD);
        float inv = rsqrtf(var + 1e-12f);
        float lo = 0.f;
        #pragma unroll
        for (int j = 0; j < GD; ++j)
            lo = fmaf(fmaf((o[l][j] - mu) * inv, s_lng[j], s_lnb[j]), s_lw[j], lo);
        lg[l] = (lo + s_lb) * (1.0f / 0.8f);
    }
    float mx = fmaxf(lg[0], fmaxf(lg[1], lg[2]));
    float e0 = __expf(lg[0] - mx), e1 = __expf(lg[1] - mx), e2 = __expf(lg[2] - mx);
    float inv = 1.f / (e0 + e1 + e2);
    float w0 = e0 * inv, w1 = e1 * inv, w2 = e2 * inv;

    float4* o4 = (float4*)(out + (size_t)b * D64);
    #pragma unroll
    for (int q = 0; q < 16; ++q) {
        float4 a = p0[q], bb = p1[q], c = p2[q], r;
        r.x = w0 * a.x + w1 * bb.x + w2 * c.x;
        r.y = w0 * a.y + w1 * bb.y + w2 * c.y;
        r.z = w0 * a.z + w1 * bb.z + w2 * c.z;
        r.w = w0 * a.w + w1 * bb.w + w2 * c.w;
        o4[q] = r;
    }
}

extern "C" void kernel_launch(void* const* d_in, const int* in_sizes, int n_in,
                              void* d_out, int out_size, void* d_ws, size_t ws_size,
                              hipStream_t stream) {
    const float* user      = (const float*)d_in[0];
    const float* item      = (const float*)d_in[1];
    const int*   erow      = (const int*)  d_in[2];
    const int*   ecol      = (const int*)  d_in[3];
    const float* eval_     = (const float*)d_in[4];
    const int*   nids      = (const int*)  d_in[5];
    const float* down_w    = (const float*)d_in[6];
    const float* in_proj_w = (const float*)d_in[7];
    const float* conv_w    = (const float*)d_in[8];
    const float* conv_b    = (const float*)d_in[9];
    const float* x_proj_w  = (const float*)d_in[10];
    const float* dt_proj_w = (const float*)d_in[11];
    const float* dt_proj_b = (const float*)d_in[12];
    const float* A_log     = (const float*)d_in[13];
    const float* D_param   = (const float*)d_in[14];
    const float* out_projw = (const float*)d_in[15];
    const float* ln_g      = (const float*)d_in[16];
    const float* ln_b      = (const float*)d_in[17];
    const float* to_lw     = (const float*)d_in[18];
    const float* to_lb     = (const float*)d_in[19];
    float* out = (float*)d_out;

    // workspace layout (~87 MB total)
    char* base = (char*)d_ws;
    float* embA  = (float*)base;                                   // 64,000,000
    float* embBc = (float*)(base + 64000000);                      //  4,194,304
    char* c = base + 64000000 + 4194304;
    // cnt + nidf + needf contiguous for one zero pass (1,500,032 B, 16-aligned)
    int* cnt = (int*)c;                                            // 1,000,000
    unsigned char* nidf  = (unsigned char*)(c + 1000000);          //   250,000
    unsigned char* needf = (unsigned char*)(c + 1250000);          //   250,032 (padded)
    c += 1500032;
    int* offs = (int*)c;  c += (size_t)(NTOT + 1) * 4 + 60;        // 1,000,064
    int* bsum = (int*)c;  c += 1024;
    int* slot = (int*)c;  c += (size_t)NNZ * 4;                    // 5,000,000
    int2* colval = (int2*)c;                                       // 10,000,000

    // ---- flags + counters ----
    zero4_kernel<<<(1500032 / 16 + 255) / 256, 256, 0, stream>>>((int4*)cnt, 1500032 / 16);
    mark_nids_kernel<<<(BATCH + 255) / 256, 256, 0, stream>>>(nids, nidf, needf);
    mark_need_kernel<<<(NNZ + 255) / 256, 256, 0, stream>>>(erow, ecol, nidf, needf);

    // ---- build (sparse) CSR ----
    hist_slot_kernel<<<(NNZ + 255) / 256, 256, 0, stream>>>(erow, needf, cnt, slot);
    scan1_kernel<<<NBLK1, 256, 0, stream>>>(cnt, offs, bsum);
    scan2_kernel<<<1, 256, 0, stream>>>(bsum);
    scan3_kernel<<<(NTOT + 255) / 256, 256, 0, stream>>>(offs, bsum, cnt);
    fill_kernel<<<(NNZ + 255) / 256, 256, 0, stream>>>(erow, ecol, eval_, offs, slot, needf, colval);

    // ---- layer 1 (needed rows only) + layer 2 (node_ids rows only) ----
    layer1_kernel<<<NTOT / 16, 256, 0, stream>>>(user, item, needf, offs, colval, embA);
    layer2_kernel<<<BATCH / 16, 256, 0, stream>>>(embA, nids, offs, colval, embBc);

    // ---- fused head ----
    final_kernel<<<BATCH / 64, 64, 0, stream>>>(nids, user, item, embA, embBc,
                                                down_w, in_proj_w, conv_w, conv_b,
                                                x_proj_w, dt_proj_w, dt_proj_b, A_log,
                                                D_param, out_projw, ln_g, ln_b, to_lw, to_lb, out);
}

// Round 5
// 266.197 us; speedup vs baseline: 3.9675x; 1.0933x over previous
//
#include <hip/hip_runtime.h>
#include <math.h>

#define N_USER 100000
#define N_ITEM 150000
#define NTOT   250000
#define D64    64
#define NNZ    1250000
#define BATCH  16384
#define GD     16
#define DSTATE 8
#define DCONV  4
#define DINNER 32
#define LSEQ   3
#define NBLK1  ((NTOT + 1023) >> 10)   // 245 scan blocks

// ---------------- zero fill for cnt+flags region (int4-wide) ---------------
__global__ void zero4_kernel(int4* __restrict__ p, int n4) {
    int i = blockIdx.x * blockDim.x + threadIdx.x;
    if (i < n4) p[i] = make_int4(0, 0, 0, 0);
}

// ---------------- mark node_ids rows ---------------------------------------
__global__ void mark_nids_kernel(const int* __restrict__ nids,
                                 unsigned char* __restrict__ nidf,
                                 unsigned char* __restrict__ needf) {
    int b = blockIdx.x * 256 + threadIdx.x;
    if (b < BATCH) { int r = nids[b]; nidf[r] = 1; needf[r] = 1; }
}

// ---------------- mark cols needed as layer-2 sources ----------------------
__global__ void mark_need_kernel(const int* __restrict__ erow,
                                 const int* __restrict__ ecol,
                                 const unsigned char* __restrict__ nidf,
                                 unsigned char* __restrict__ needf) {
    int e = blockIdx.x * 256 + threadIdx.x;
    if (e < NNZ && nidf[erow[e]]) needf[ecol[e]] = 1;
}

// ---------------- histogram + slot assignment (needed edges only) ----------
__global__ void hist_slot_kernel(const int* __restrict__ erow,
                                 const unsigned char* __restrict__ needf,
                                 int* __restrict__ cnt, int* __restrict__ slot) {
    int e = blockIdx.x * 256 + threadIdx.x;
    if (e >= NNZ) return;
    int r = erow[e];
    if (needf[r]) slot[e] = atomicAdd(&cnt[r], 1);
}

// ---------------- exclusive scan of cnt -> offs (3-kernel) -----------------
__global__ __launch_bounds__(256) void scan1_kernel(const int* __restrict__ cnt,
                                                    int* __restrict__ offs,
                                                    int* __restrict__ bsum) {
    __shared__ int lds[256];
    int t = threadIdx.x;
    int base = (blockIdx.x << 10) + (t << 2);
    int d0 = (base + 0 < NTOT) ? cnt[base + 0] : 0;
    int d1 = (base + 1 < NTOT) ? cnt[base + 1] : 0;
    int d2 = (base + 2 < NTOT) ? cnt[base + 2] : 0;
    int d3 = (base + 3 < NTOT) ? cnt[base + 3] : 0;
    int s = d0 + d1 + d2 + d3;
    lds[t] = s;
    __syncthreads();
    for (int off = 1; off < 256; off <<= 1) {
        int v = (t >= off) ? lds[t - off] : 0;
        __syncthreads();
        lds[t] += v;
        __syncthreads();
    }
    int excl = lds[t] - s;
    if (base + 0 < NTOT) offs[base + 0] = excl;
    if (base + 1 < NTOT) offs[base + 1] = excl + d0;
    if (base + 2 < NTOT) offs[base + 2] = excl + d0 + d1;
    if (base + 3 < NTOT) offs[base + 3] = excl + d0 + d1 + d2;
    if (t == 255) bsum[blockIdx.x] = lds[255];
}

__global__ __launch_bounds__(256) void scan2_kernel(int* __restrict__ bsum) {
    __shared__ int lds[256];
    int t = threadIdx.x;
    int v0 = (t < NBLK1) ? bsum[t] : 0;
    lds[t] = v0;
    __syncthreads();
    for (int off = 1; off < 256; off <<= 1) {
        int v = (t >= off) ? lds[t - off] : 0;
        __syncthreads();
        lds[t] += v;
        __syncthreads();
    }
    if (t < NBLK1) bsum[t] = lds[t] - v0;
}

__global__ void scan3_kernel(int* __restrict__ offs, const int* __restrict__ bsum,
                             const int* __restrict__ cnt) {
    int i = blockIdx.x * 256 + threadIdx.x;
    if (i >= NTOT) return;
    int v = offs[i] + bsum[i >> 10];
    offs[i] = v;
    if (i == NTOT - 1) offs[NTOT] = v + cnt[i];
}

// ---------------- CSR fill: atomic-free, needed edges only -----------------
__global__ void fill_kernel(const int* __restrict__ erow, const int* __restrict__ ecol,
                            const float* __restrict__ eval_, const int* __restrict__ offs,
                            const int* __restrict__ slot,
                            const unsigned char* __restrict__ needf,
                            int2* __restrict__ colval) {
    int e = blockIdx.x * 256 + threadIdx.x;
    if (e >= NNZ) return;
    int r = erow[e];
    if (!needf[r]) return;
    colval[offs[r] + slot[e]] = make_int2(ecol[e], __float_as_int(eval_[e]));
}

// ---------------- layer 1: quarter-wave per row, needed rows only ----------
__global__ __launch_bounds__(256) void layer1_kernel(const float* __restrict__ user,
                                                     const float* __restrict__ item,
                                                     const unsigned char* __restrict__ needf,
                                                     const int*  __restrict__ offs,
                                                     const int2* __restrict__ colval,
                                                     float* __restrict__ dst) {
    const float4* user4 = (const float4*)user;
    const float4* item4 = (const float4*)item;

    int row    = (blockIdx.x << 4) + (threadIdx.x >> 4);
    int lane16 = threadIdx.x & 15;
    if (row >= NTOT) return;
    if (!needf[row]) return;
    int o0 = offs[row], o1 = offs[row + 1];

    float4 acc = make_float4(0.f, 0.f, 0.f, 0.f);
    int i = o0;
    for (; i + 2 <= o1; i += 2) {
        int2 cv0 = colval[i];
        int2 cv1 = colval[i + 1];
        const float4* s0 = (cv0.x < N_USER) ? user4 + (size_t)cv0.x * 16
                                            : item4 + (size_t)(cv0.x - N_USER) * 16;
        const float4* s1 = (cv1.x < N_USER) ? user4 + (size_t)cv1.x * 16
                                            : item4 + (size_t)(cv1.x - N_USER) * 16;
        float4 v0 = s0[lane16];
        float4 v1 = s1[lane16];
        float w0 = __int_as_float(cv0.y);
        float w1 = __int_as_float(cv1.y);
        acc.x = fmaf(w1, v1.x, fmaf(w0, v0.x, acc.x));
        acc.y = fmaf(w1, v1.y, fmaf(w0, v0.y, acc.y));
        acc.z = fmaf(w1, v1.z, fmaf(w0, v0.z, acc.z));
        acc.w = fmaf(w1, v1.w, fmaf(w0, v0.w, acc.w));
    }
    if (i < o1) {
        int2 cv = colval[i];
        const float4* s0 = (cv.x < N_USER) ? user4 + (size_t)cv.x * 16
                                           : item4 + (size_t)(cv.x - N_USER) * 16;
        float4 v = s0[lane16];
        float w = __int_as_float(cv.y);
        acc.x = fmaf(w, v.x, acc.x);
        acc.y = fmaf(w, v.y, acc.y);
        acc.z = fmaf(w, v.z, acc.z);
        acc.w = fmaf(w, v.w, acc.w);
    }

    float s = fmaf(acc.x, acc.x, fmaf(acc.y, acc.y, fmaf(acc.z, acc.z, acc.w * acc.w)));
    #pragma unroll
    for (int m = 8; m >= 1; m >>= 1) s += __shfl_xor(s, m, 64);
    float scale = 1.f / fmaxf(sqrtf(s), 1e-12f);
    float4 r;
    r.x = acc.x * scale; r.y = acc.y * scale; r.z = acc.z * scale; r.w = acc.w * scale;
    ((float4*)dst)[(size_t)row * 16 + lane16] = r;
}

// ---------------- layer 2: only node_ids rows, compact output --------------
__global__ __launch_bounds__(256) void layer2_kernel(const float* __restrict__ embA,
                                                     const int*  __restrict__ nids,
                                                     const int*  __restrict__ offs,
                                                     const int2* __restrict__ colval,
                                                     float* __restrict__ embBc) {
    const float4* src4 = (const float4*)embA;
    int idx    = (blockIdx.x << 4) + (threadIdx.x >> 4);
    int lane16 = threadIdx.x & 15;
    if (idx >= BATCH) return;
    int row = nids[idx];
    int o0 = offs[row], o1 = offs[row + 1];

    float4 acc = make_float4(0.f, 0.f, 0.f, 0.f);
    int i = o0;
    for (; i + 2 <= o1; i += 2) {
        int2 cv0 = colval[i];
        int2 cv1 = colval[i + 1];
        float4 v0 = src4[(size_t)cv0.x * 16 + lane16];
        float4 v1 = src4[(size_t)cv1.x * 16 + lane16];
        float w0 = __int_as_float(cv0.y);
        float w1 = __int_as_float(cv1.y);
        acc.x = fmaf(w1, v1.x, fmaf(w0, v0.x, acc.x));
        acc.y = fmaf(w1, v1.y, fmaf(w0, v0.y, acc.y));
        acc.z = fmaf(w1, v1.z, fmaf(w0, v0.z, acc.z));
        acc.w = fmaf(w1, v1.w, fmaf(w0, v0.w, acc.w));
    }
    if (i < o1) {
        int2 cv = colval[i];
        float4 v = src4[(size_t)cv.x * 16 + lane16];
        float w = __int_as_float(cv.y);
        acc.x = fmaf(w, v.x, acc.x);
        acc.y = fmaf(w, v.y, acc.y);
        acc.z = fmaf(w, v.z, acc.z);
        acc.w = fmaf(w, v.w, acc.w);
    }

    float s = fmaf(acc.x, acc.x, fmaf(acc.y, acc.y, fmaf(acc.z, acc.z, acc.w * acc.w)));
    #pragma unroll
    for (int m = 8; m >= 1; m >>= 1) s += __shfl_xor(s, m, 64);
    float scale = 1.f / fmaxf(sqrtf(s), 1e-12f);
    float4 r;
    r.x = acc.x * scale; r.y = acc.y * scale; r.z = acc.z * scale; r.w = acc.w * scale;
    ((float4*)embBc)[(size_t)idx * 16 + lane16] = r;
}

// ---------------- fused head: 16 lanes per batch element -------------------
// Block = 256 threads = 16 elements -> 1024 blocks, 4096 waves, ~16 waves/CU
// (vs 1 wave/CU for the old thread-per-element version -> latency now hidden
// by TLP). All lane-varying LDS layouts transposed for conflict-free access.
// Strides chosen so the 4 element-groups of a wave hit distinct banks:
//   rows 196 floats (off 4), g/dbc 49 (off 17), xs 98 (off 2).
__global__ __launch_bounds__(256) void final_kernel(
    const int*   __restrict__ nids,
    const float* __restrict__ user,      const float* __restrict__ item,
    const float* __restrict__ embA,      const float* __restrict__ embBc,
    const float* __restrict__ down_w,    const float* __restrict__ in_proj_w,
    const float* __restrict__ conv_w,    const float* __restrict__ conv_b,
    const float* __restrict__ x_proj_w,  const float* __restrict__ dt_proj_w,
    const float* __restrict__ dt_proj_b, const float* __restrict__ A_log,
    const float* __restrict__ D_param,   const float* __restrict__ out_proj_w,
    const float* __restrict__ ln_g,      const float* __restrict__ ln_b,
    const float* __restrict__ to_logit_w,const float* __restrict__ to_logit_b,
    float* __restrict__ out) {

    __shared__ float4 s_rows4[16 * 49];      // 16 elem x 3 rows x 64f (stride 196f)
    __shared__ float  s_downT[D64 * GD];     // [d][j]
    __shared__ float  s_ipxT[GD * DINNER];   // [j][d]
    __shared__ float  s_ipzT[GD * DINNER];   // [j][d]
    __shared__ float  s_xpT[DINNER * 17];    // [d][r]
    __shared__ float  s_opT[DINNER * GD];    // [d][j]
    __shared__ float  s_AT[DSTATE * DINNER]; // [s][d] = -exp(A_log)
    __shared__ float4 s_cw4[DINNER];
    __shared__ float  s_cb[DINNER], s_dtw[DINNER], s_dtb[DINNER], s_Dp[DINNER];
    __shared__ float  s_lng[GD], s_lnb[GD], s_lw[GD];
    __shared__ float  s_lb;
    __shared__ float  s_g[16 * 49];          // 48 g per elem (stride 49)
    __shared__ float  s_xs[16 * 98];         // xs then ys (stride 98)
    __shared__ float  s_dbc[16 * 49];        // 51 dbc per elem (stride 49)

    int t = threadIdx.x;

    // ---- stage + transpose weights ----
    for (int i = t; i < D64 * GD; i += 256) {        // downT[d*16+j] = down[j][d]
        int j = i & 15, d = i >> 4;
        s_downT[i] = down_w[j * D64 + d];
    }
    for (int i = t; i < GD * DINNER; i += 256) {     // ipxT[j*32+d] = ip[d][j]
        int d = i & 31, j = i >> 5;
        s_ipxT[i] = in_proj_w[d * GD + j];
        s_ipzT[i] = in_proj_w[(d + DINNER) * GD + j];
    }
    for (int i = t; i < DINNER * 17; i += 256) {     // xpT[d*17+r] = xp[r][d]
        int d = i / 17, r = i % 17;
        s_xpT[i] = x_proj_w[r * DINNER + d];
    }
    for (int i = t; i < DINNER * GD; i += 256) {     // opT[d*16+j] = op[j][d]
        int j = i & 15, d = i >> 4;
        s_opT[i] = out_proj_w[j * DINNER + d];
    }
    for (int i = t; i < DSTATE * DINNER; i += 256) { // AT[s*32+d]
        int d = i & 31, s = i >> 5;
        s_AT[i] = -expf(A_log[d * DSTATE + s]);
    }
    if (t < DINNER) {
        s_cw4[t] = ((const float4*)conv_w)[t];
        s_cb[t] = conv_b[t]; s_dtw[t] = dt_proj_w[t];
        s_dtb[t] = dt_proj_b[t]; s_Dp[t] = D_param[t];
    }
    if (t < GD) { s_lng[t] = ln_g[t]; s_lnb[t] = ln_b[t]; s_lw[t] = to_logit_w[t]; }
    if (t == 0) s_lb = to_logit_b[0];

    // ---- stage the 3 sequence rows of this block's 16 elements ----
    int wave = t >> 6, lane = t & 63;
    int grp = lane >> 4, lane16 = lane & 15;
    int eb = wave * 4 + grp;                      // element in block, 0..15
    int b  = blockIdx.x * 16 + eb;                // global batch element
    {
        int nid = nids[b];
        const float4* p0 = (const float4*)((nid < N_USER) ? user + (size_t)nid * D64
                                                          : item + (size_t)(nid - N_USER) * D64);
        const float4* p1 = (const float4*)(embA + (size_t)nid * D64);
        const float4* p2 = (const float4*)(embBc + (size_t)b * D64);
        s_rows4[eb * 49 + 0 * 16 + lane16] = p0[lane16];
        s_rows4[eb * 49 + 1 * 16 + lane16] = p1[lane16];
        s_rows4[eb * 49 + 2 * 16 + lane16] = p2[lane16];
    }
    __syncthreads();

    const float* rows = (const float*)s_rows4 + eb * 196;

    // ---- g[l][j]: lane j computes 3 dot-64s ----
    {
        float a0 = 0.f, a1 = 0.f, a2 = 0.f;
        #pragma unroll
        for (int d = 0; d < D64; ++d) {
            float w = s_downT[d * GD + lane16];
            a0 = fmaf(rows[d], w, a0);
            a1 = fmaf(rows[64 + d], w, a1);
            a2 = fmaf(rows[128 + d], w, a2);
        }
        s_g[eb * 49 + 0 * GD + lane16] = a0;
        s_g[eb * 49 + 1 * GD + lane16] = a1;
        s_g[eb * 49 + 2 * GD + lane16] = a2;
    }
    __syncthreads();

    const float* ge = s_g + eb * 49;

    // ---- xl -> conv -> silu for this lane's 2 channels ----
    float xsr[2][LSEQ];
    #pragma unroll
    for (int c = 0; c < 2; ++c) {
        int d = lane16 + 16 * c;
        float xl0 = 0.f, xl1 = 0.f, xl2 = 0.f;
        #pragma unroll
        for (int j = 0; j < GD; ++j) {
            float w = s_ipxT[j * DINNER + d];
            xl0 = fmaf(ge[j], w, xl0);
            xl1 = fmaf(ge[GD + j], w, xl1);
            xl2 = fmaf(ge[2 * GD + j], w, xl2);
        }
        float4 cw = s_cw4[d]; float cb = s_cb[d];
        float a0 = fmaf(xl0, cw.w, cb);
        float a1 = fmaf(xl1, cw.w, fmaf(xl0, cw.z, cb));
        float a2 = fmaf(xl2, cw.w, fmaf(xl1, cw.z, fmaf(xl0, cw.y, cb)));
        xsr[c][0] = a0 / (1.f + __expf(-a0));
        xsr[c][1] = a1 / (1.f + __expf(-a1));
        xsr[c][2] = a2 / (1.f + __expf(-a2));
        #pragma unroll
        for (int l = 0; l < LSEQ; ++l) s_xs[eb * 98 + l * DINNER + d] = xsr[c][l];
    }
    __syncthreads();

    // ---- dbc[l][r] = sum_d xs[l][d] * xp[r][d] : lane r (lane 0 also r=16) --
    {
        const float* xse = s_xs + eb * 98;
        int nr = (lane16 == 0) ? 2 : 1;
        for (int it = 0; it < nr; ++it) {
            int r = (it == 0) ? lane16 : 16;
            float a0 = 0.f, a1 = 0.f, a2 = 0.f;
            #pragma unroll
            for (int d = 0; d < DINNER; ++d) {
                float w = s_xpT[d * 17 + r];
                a0 = fmaf(xse[d], w, a0);
                a1 = fmaf(xse[DINNER + d], w, a1);
                a2 = fmaf(xse[2 * DINNER + d], w, a2);
            }
            s_dbc[eb * 49 + 0 * 17 + r] = a0;
            s_dbc[eb * 49 + 1 * 17 + r] = a1;
            s_dbc[eb * 49 + 2 * 17 + r] = a2;
        }
    }
    __syncthreads();

    // ---- selective scan + z-gate; write ys over the xs slots ----
    {
        const float* dbce = s_dbc + eb * 49;
        float h[2][DSTATE];
        #pragma unroll
        for (int c = 0; c < 2; ++c)
            #pragma unroll
            for (int s = 0; s < DSTATE; ++s) h[c][s] = 0.f;
        #pragma unroll
        for (int l = 0; l < LSEQ; ++l) {
            float dtr = dbce[l * 17];
            float Bm[DSTATE], Cm[DSTATE];
            #pragma unroll
            for (int s = 0; s < DSTATE; ++s) {
                Bm[s] = dbce[l * 17 + 1 + s];
                Cm[s] = dbce[l * 17 + 9 + s];
            }
            #pragma unroll
            for (int c = 0; c < 2; ++c) {
                int d = lane16 + 16 * c;
                float pre = fmaf(dtr, s_dtw[d], s_dtb[d]);
                float dt  = (pre > 20.f) ? pre : __logf(1.f + __expf(pre));
                float xv  = xsr[c][l];
                float dtx = dt * xv;
                float acc = 0.f;
                #pragma unroll
                for (int s = 0; s < DSTATE; ++s) {
                    float dA = __expf(dt * s_AT[s * DINNER + d]);
                    h[c][s] = fmaf(dA, h[c][s], dtx * Bm[s]);
                    acc = fmaf(h[c][s], Cm[s], acc);
                }
                float y = fmaf(s_Dp[d], xv, acc);
                float zv = 0.f;
                #pragma unroll
                for (int j = 0; j < GD; ++j)
                    zv = fmaf(ge[l * GD + j], s_ipzT[j * DINNER + d], zv);
                float ys = y * (zv / (1.f + __expf(-zv)));
                s_xs[eb * 98 + l * DINNER + d] = ys;   // own slot; xs kept in regs
            }
        }
    }
    __syncthreads();

    // ---- out_proj: lane j: o[l][j] = sum_d ys[l][d]*op[j][d]; + LN + logit --
    float lg[LSEQ];
    {
        const float* yse = s_xs + eb * 98;
        #pragma unroll
        for (int l = 0; l < LSEQ; ++l) {
            float a = 0.f;
            #pragma unroll
            for (int d = 0; d < DINNER; ++d)
                a = fmaf(yse[l * DINNER + d], s_opT[d * GD + lane16], a);
            float v = a + ge[l * GD + lane16];
            float sm = v, sq = v * v;
            #pragma unroll
            for (int m = 1; m <= 8; m <<= 1) {
                sm += __shfl_xor(sm, m, 64);
                sq += __shfl_xor(sq, m, 64);
            }
            float mu  = sm * (1.f / GD);
            float var = fmaxf(sq * (1.f / GD) - mu * mu, 0.f);
            float inv = rsqrtf(var + 1e-12f);
            float lo = fmaf(fmaf((v - mu) * inv, s_lng[lane16], s_lnb[lane16]),
                            s_lw[lane16], 0.f);
            #pragma unroll
            for (int m = 1; m <= 8; m <<= 1) lo += __shfl_xor(lo, m, 64);
            lg[l] = (lo + s_lb) * 1.25f;   // /TEMP=0.8
        }
    }

    // ---- softmax over l + weighted fuse of the 3 staged rows ----
    {
        float mx = fmaxf(lg[0], fmaxf(lg[1], lg[2]));
        float e0 = __expf(lg[0] - mx), e1 = __expf(lg[1] - mx), e2 = __expf(lg[2] - mx);
        float inv = 1.f / (e0 + e1 + e2);
        float w0 = e0 * inv, w1 = e1 * inv, w2 = e2 * inv;
        float4 r0 = s_rows4[eb * 49 + 0 * 16 + lane16];
        float4 r1 = s_rows4[eb * 49 + 1 * 16 + lane16];
        float4 r2 = s_rows4[eb * 49 + 2 * 16 + lane16];
        float4 r;
        r.x = w0 * r0.x + w1 * r1.x + w2 * r2.x;
        r.y = w0 * r0.y + w1 * r1.y + w2 * r2.y;
        r.z = w0 * r0.z + w1 * r1.z + w2 * r2.z;
        r.w = w0 * r0.w + w1 * r1.w + w2 * r2.w;
        ((float4*)out)[(size_t)b * 16 + lane16] = r;
    }
}

extern "C" void kernel_launch(void* const* d_in, const int* in_sizes, int n_in,
                              void* d_out, int out_size, void* d_ws, size_t ws_size,
                              hipStream_t stream) {
    const float* user      = (const float*)d_in[0];
    const float* item      = (const float*)d_in[1];
    const int*   erow      = (const int*)  d_in[2];
    const int*   ecol      = (const int*)  d_in[3];
    const float* eval_     = (const float*)d_in[4];
    const int*   nids      = (const int*)  d_in[5];
    const float* down_w    = (const float*)d_in[6];
    const float* in_proj_w = (const float*)d_in[7];
    const float* conv_w    = (const float*)d_in[8];
    const float* conv_b    = (const float*)d_in[9];
    const float* x_proj_w  = (const float*)d_in[10];
    const float* dt_proj_w = (const float*)d_in[11];
    const float* dt_proj_b = (const float*)d_in[12];
    const float* A_log     = (const float*)d_in[13];
    const float* D_param   = (const float*)d_in[14];
    const float* out_projw = (const float*)d_in[15];
    const float* ln_g      = (const float*)d_in[16];
    const float* ln_b      = (const float*)d_in[17];
    const float* to_lw     = (const float*)d_in[18];
    const float* to_lb     = (const float*)d_in[19];
    float* out = (float*)d_out;

    // workspace layout (~87 MB total)
    char* base = (char*)d_ws;
    float* embA  = (float*)base;                                   // 64,000,000
    float* embBc = (float*)(base + 64000000);                      //  4,194,304
    char* c = base + 64000000 + 4194304;
    int* cnt = (int*)c;                                            // 1,000,000
    unsigned char* nidf  = (unsigned char*)(c + 1000000);          //   250,000
    unsigned char* needf = (unsigned char*)(c + 1250000);          //   250,032
    c += 1500032;
    int* offs = (int*)c;  c += (size_t)(NTOT + 1) * 4 + 60;        // 1,000,064
    int* bsum = (int*)c;  c += 1024;
    int* slot = (int*)c;  c += (size_t)NNZ * 4;                    // 5,000,000
    int2* colval = (int2*)c;                                       // 10,000,000

    // ---- flags + counters ----
    zero4_kernel<<<(1500032 / 16 + 255) / 256, 256, 0, stream>>>((int4*)cnt, 1500032 / 16);
    mark_nids_kernel<<<(BATCH + 255) / 256, 256, 0, stream>>>(nids, nidf, needf);
    mark_need_kernel<<<(NNZ + 255) / 256, 256, 0, stream>>>(erow, ecol, nidf, needf);

    // ---- build (sparse) CSR ----
    hist_slot_kernel<<<(NNZ + 255) / 256, 256, 0, stream>>>(erow, needf, cnt, slot);
    scan1_kernel<<<NBLK1, 256, 0, stream>>>(cnt, offs, bsum);
    scan2_kernel<<<1, 256, 0, stream>>>(bsum);
    scan3_kernel<<<(NTOT + 255) / 256, 256, 0, stream>>>(offs, bsum, cnt);
    fill_kernel<<<(NNZ + 255) / 256, 256, 0, stream>>>(erow, ecol, eval_, offs, slot, needf, colval);

    // ---- layer 1 (needed rows only) + layer 2 (node_ids rows only) ----
    layer1_kernel<<<NTOT / 16, 256, 0, stream>>>(user, item, needf, offs, colval, embA);
    layer2_kernel<<<BATCH / 16, 256, 0, stream>>>(embA, nids, offs, colval, embBc);

    // ---- fused head: 16 elements per 256-thread block ----
    final_kernel<<<BATCH / 16, 256, 0, stream>>>(nids, user, item, embA, embBc,
                                                 down_w, in_proj_w, conv_w, conv_b,
                                                 x_proj_w, dt_proj_w, dt_proj_b, A_log,
                                                 D_param, out_projw, ln_g, ln_b, to_lw, to_lb, out);
}